// Round 10
// baseline (217.113 us; speedup 1.0000x reference)
//
#include <hip/hip_runtime.h>
#include <stdint.h>
#include <math.h>

// ReformerAttention on MI355X — fp32 I/O. B=2,T=2048,E=512,H=8,Dh=64,
// 2 hash rounds, buckets<32 attend.
// Projection row p = logical (b'=p>>11, t'=p&2047); gathers input row (b=p&1, t=p>>1).
//
// 7 launches:
//   prep (fp16 2-way split of q/k/v/Wq/Wk/Wv + bf16 hi/lo Wo, TILED dest-linear;
//         + lshW split + zero attn/cnt)
//   -> proj_mfma (fused Q,K,V projections, fp16 3-term, tiled operands)
//   -> hash_mfma(+hist) -> scan(+tasks, 32-q) -> scatter2
//   -> attn_task (MFMA, 32-query tasks; writes attn in TILED fp32 layout)
//   -> mfma_gemm(out, tiled-A + tiled-B, perm)
//
// r9 lessons: line model 3-for-3 (proj r6, outproj r8, prep r9). Harness
//   issues ~2x 256MiB fills/iter (~90us) — uncontrollable. Remaining big
//   OURS: attn_task. Its 16-query tasks re-read each bucket's K/V lists
//   ~nq/16 times via inherently scattered gathers (16 lines/load-instr).
//   v10: 32-query tasks — halves scattered K/V bytes AND divergent-load
//   instruction count. MFMA count per K-frag doubles (cheap). LDS 26KB
//   (6 blocks/CU). Per-query arithmetic identical.
// Tiled layouts (elem offsets, fp16/bf16/fp32 units):
//   A[mb][ks][half]: ((mb*32 + ks*2 + half)*64 + lane)*8,
//     row=mb*32+half*16+(lane&15), k=ks*32+(lane>>4)*8
//   B[nb][ks]: ((nb*16 + ks)*64 + lane)*8, col=nb*16+(lane&15), k=ks*32+(lane>>4)*8
// Q,K precision: x = h + l/4096 fp16 split (verified r2-r9, argmax-safe).
// scan v4: shfl prefix scans, ONE atomicAdd per wave, 32-q task emission.
// hash v4 (r4): 3-term fp16 MFMA + in-reg argmax.

#define T_ 2048
#define E_ 512
#define H_ 8
#define DH_ 64
#define B_ 2
#define M_ 4096
#define NROUND 2
#define NBUCKET 32
#define NSEG 32
#define MAXTASK 5120

typedef short v8s __attribute__((ext_vector_type(8)));
typedef _Float16 v8h __attribute__((ext_vector_type(8)));
typedef float v4f __attribute__((ext_vector_type(4)));

__device__ __forceinline__ float bf2f(uint16_t u) {
  union { uint32_t i; float f; } v; v.i = ((uint32_t)u) << 16; return v.f;
}
__device__ __forceinline__ uint16_t f2bf(float f) {
  union { float fv; uint32_t i; } v; v.fv = f;
  uint32_t x = v.i;
  x += 0x7fffu + ((x >> 16) & 1u);   // RN-even
  return (uint16_t)(x >> 16);
}
__device__ __forceinline__ void split8(const float4 a, const float4 b,
                                       v8s& h, v8s& l) {
  const float x[8] = {a.x, a.y, a.z, a.w, b.x, b.y, b.z, b.w};
#pragma unroll
  for (int j = 0; j < 8; j++) {
    const uint16_t hh = f2bf(x[j]);
    h[j] = (short)hh;
    l[j] = (short)f2bf(x[j] - bf2f(hh));
  }
}
// 2-way fp16 split with scaled residual: x = h + l*2^-12, no fp16 subnormals.
__device__ __forceinline__ void split2h8(const float4 a, const float4 b,
                                         v8h& h, v8h& l) {
  const float x[8] = {a.x, a.y, a.z, a.w, b.x, b.y, b.z, b.w};
#pragma unroll
  for (int j = 0; j < 8; j++) {
    const float xv = x[j];
    const _Float16 hh = (fabsf(xv) < 6.1035156e-5f) ? (_Float16)0.0f
                                                    : (_Float16)xv;
    const float r = xv - (float)hh;          // exact (Sterbenz / hh==0)
    h[j] = hh;
    l[j] = (_Float16)(r * 4096.0f);
  }
}

// ---------------------------------------------------------------------------
// prep v9: staging into tiled fragment layouts, DEST-LINEAR (stores are
// contiguous 1KB/instr; strided reads get L1/L2 reuse within a block).
//   blocks [0,384)     : q/k/v fp16 split, gathered, tiled (block per mb)
//   blocks [384,896)   : Wq/Wk/Wv fp16 + Wo bf16 splits, tiled
//   blocks [896,1920)  : zero attn
//   block  1920        : zero cnt region + lshW fp16 split
// ---------------------------------------------------------------------------
__global__ __launch_bounds__(256) void prep_kernel(
    const float* __restrict__ Xq, const float* __restrict__ Xk,
    const float* __restrict__ Xv,
    const float* __restrict__ Wq, const float* __restrict__ Wk,
    const float* __restrict__ Wv, const float* __restrict__ Wo,
    const float* __restrict__ lshW,
    uint16_t* __restrict__ Xqh, uint16_t* __restrict__ Xql,
    uint16_t* __restrict__ Xkh, uint16_t* __restrict__ Xkl,
    uint16_t* __restrict__ Xvh, uint16_t* __restrict__ Xvl,
    uint16_t* __restrict__ Wqh, uint16_t* __restrict__ Wql,
    uint16_t* __restrict__ Wkh, uint16_t* __restrict__ Wkl,
    uint16_t* __restrict__ Wvh, uint16_t* __restrict__ Wvl,
    uint16_t* __restrict__ Woh, uint16_t* __restrict__ Wol,
    uint16_t* __restrict__ Lwh, uint16_t* __restrict__ Lwl,
    float* __restrict__ attn, int* __restrict__ cnt)
{
  const int bid = blockIdx.x;
  const int tid = threadIdx.x;

  if (bid < 384) {                       // q/k/v fp16 split (gathered, tiled)
    const int sel = bid >> 7;            // 0=q,1=k,2=v
    const int mb  = bid & 127;           // 32-row block
    const float* X = (sel == 0) ? Xq : (sel == 1) ? Xk : Xv;
    uint16_t* H = (sel == 0) ? Xqh : (sel == 1) ? Xkh : Xvh;
    uint16_t* L = (sel == 0) ? Xql : (sel == 1) ? Xkl : Xvl;
#pragma unroll
    for (int it = 0; it < 8; it++) {
      const int g = it * 256 + tid;      // chunk within mb: [0,2048)
      const int f = g >> 6;              // frag 0..31 (ks*2+half)
      const int lane = g & 63;
      const int ks = f >> 1, half = f & 1;
      const int p = mb * 32 + half * 16 + (lane & 15);
      const int k = ks * 32 + (lane >> 4) * 8;
      const long src = ((long)(p & 1) * T_ + (p >> 1)) * E_ + k;
      const float4 a = *(const float4*)(X + src);
      const float4 b = *(const float4*)(X + src + 4);
      v8h h, l;
      split2h8(a, b, h, l);
      const long dst = (long)mb * 16384 + (long)g * 8;
      *(v8h*)(H + dst) = h;
      *(v8h*)(L + dst) = l;
    }
    return;
  }

  if (bid < 896) {                       // weight splits, tiled, dest-linear
    const int wsel = (bid - 384) >> 7;   // 0=Wq,1=Wk,2=Wv,3=Wo
    const int g2 = ((bid - 384) & 127) * 256 + tid;   // chunk [0,32768)
    const int f = g2 >> 6;               // frag 0..511 (nb*16+ks)
    const int lane = g2 & 63;
    const int nb = f >> 4, ks = f & 15;
    const int n = nb * 16 + (lane & 15);
    const int k = ks * 32 + (lane >> 4) * 8;
    const long src = (long)n * E_ + k;
    const long dst = (long)g2 * 8;
    if (wsel < 3) {
      const float* S = (wsel == 0) ? Wq : (wsel == 1) ? Wk : Wv;
      const float4 a = *(const float4*)(S + src);
      const float4 b = *(const float4*)(S + src + 4);
      v8h h, l;
      split2h8(a, b, h, l);
      uint16_t* H = (wsel == 0) ? Wqh : (wsel == 1) ? Wkh : Wvh;
      uint16_t* L = (wsel == 0) ? Wql : (wsel == 1) ? Wkl : Wvl;
      *(v8h*)(H + dst) = h;
      *(v8h*)(L + dst) = l;
    } else {
      const float4 a = *(const float4*)(Wo + src);
      const float4 b = *(const float4*)(Wo + src + 4);
      v8s h, l;
      split8(a, b, h, l);
      *(v8s*)(Woh + dst) = h;
      *(v8s*)(Wol + dst) = l;
    }
    return;
  }

  if (bid < 1920) {                      // zero attn: 1024 blocks x 512 float4
    float4* a4 = (float4*)attn;
    const int g = (bid - 896) * 512 + tid * 2;
    a4[g] = make_float4(0.f, 0.f, 0.f, 0.f);
    a4[g + 1] = make_float4(0.f, 0.f, 0.f, 0.f);
    return;
  }

  for (int i = tid; i < 2 * NSEG * NBUCKET + 1; i += 256) cnt[i] = 0;
  for (int i = tid; i < NROUND * DH_ * DH_; i += 256) {  // lshW fp16 split
    const float xv = lshW[i];
    const _Float16 hh = (fabsf(xv) < 6.1035156e-5f) ? (_Float16)0.0f
                                                    : (_Float16)xv;
    const float r = xv - (float)hh;
    *(_Float16*)(Lwh + i) = hh;
    *(_Float16*)(Lwl + i) = (_Float16)(r * 4096.0f);
  }
}

// ---------------------------------------------------------------------------
// proj_mfma v6: fused Q/K/V projections, fp16 3-term, TILED operands.
// grid (32, 8, 3) = 768 blocks; 2x4 16x16 tiles/wave (32x64). Every operand
// load is lane-linear 16B (coalesced 1KB/instr). Register double-buffered.
// ---------------------------------------------------------------------------
__global__ __launch_bounds__(256) void proj_mfma(
    const uint16_t* __restrict__ Aqh, const uint16_t* __restrict__ Aql,
    const uint16_t* __restrict__ Akh, const uint16_t* __restrict__ Akl,
    const uint16_t* __restrict__ Avh, const uint16_t* __restrict__ Avl,
    const uint16_t* __restrict__ Bqh, const uint16_t* __restrict__ Bql,
    const uint16_t* __restrict__ Bkh, const uint16_t* __restrict__ Bkl,
    const uint16_t* __restrict__ Bvh, const uint16_t* __restrict__ Bvl,
    const float* __restrict__ bq, const float* __restrict__ bk,
    const float* __restrict__ bv,
    float* __restrict__ Qo, float* __restrict__ Ko, float* __restrict__ Vo)
{
  const uint16_t *Ah, *Al, *Bh, *Bl;
  const float* bias; float* C;
  if (blockIdx.z == 0)      { Ah = Aqh; Al = Aql; Bh = Bqh; Bl = Bql; bias = bq; C = Qo; }
  else if (blockIdx.z == 1) { Ah = Akh; Al = Akl; Bh = Bkh; Bl = Bkl; bias = bk; C = Ko; }
  else                      { Ah = Avh; Al = Avl; Bh = Bvh; Bl = Bvl; bias = bv; C = Vo; }

  const int wid = threadIdx.x >> 6, lane = threadIdx.x & 63;
  const int mb = blockIdx.x * 4 + wid;        // 32-row block
  const int nb0 = blockIdx.y * 4;             // first 16-col block
  const int m0 = mb * 32, n0 = blockIdx.y * 64;
  const int l15 = lane & 15, quad = lane >> 4;

  // tiled bases (fp16 elem units); frag strides: A ks*1024, half 512; B ks*512
  const long aB = (long)mb * 16384 + lane * 8;
  long bB[4];
#pragma unroll
  for (int j = 0; j < 4; j++) bB[j] = (long)(nb0 + j) * 8192 + lane * 8;

  v4f accH[2][4] = {};
  v4f accX[2][4] = {};

  // prologue: ks = 0
  v8h ah0 = *(const v8h*)(Ah + aB);
  v8h ah1 = *(const v8h*)(Ah + aB + 512);
  v8h al0 = *(const v8h*)(Al + aB);
  v8h al1 = *(const v8h*)(Al + aB + 512);
  v8h bh[4], bl[4];
#pragma unroll
  for (int j = 0; j < 4; j++) {
    bh[j] = *(const v8h*)(Bh + bB[j]);
    bl[j] = *(const v8h*)(Bl + bB[j]);
  }

  for (int ks = 0; ks < 16; ks++) {
    const int kn = (ks + 1) & 15;   // wraps on last iter; values unused
    const v8h nah0 = *(const v8h*)(Ah + aB + kn * 1024);
    const v8h nah1 = *(const v8h*)(Ah + aB + kn * 1024 + 512);
    const v8h nal0 = *(const v8h*)(Al + aB + kn * 1024);
    const v8h nal1 = *(const v8h*)(Al + aB + kn * 1024 + 512);
    v8h nbh[4], nbl[4];
#pragma unroll
    for (int j = 0; j < 4; j++) {
      nbh[j] = *(const v8h*)(Bh + bB[j] + kn * 512);
      nbl[j] = *(const v8h*)(Bl + bB[j] + kn * 512);
    }

    // 24 MFMAs: hh -> accH; h*l' and l'*h -> accX (carries 2^12 scale)
#pragma unroll
    for (int j = 0; j < 4; j++) {
      accH[0][j] = __builtin_amdgcn_mfma_f32_16x16x32_f16(ah0, bh[j], accH[0][j], 0, 0, 0);
      accH[1][j] = __builtin_amdgcn_mfma_f32_16x16x32_f16(ah1, bh[j], accH[1][j], 0, 0, 0);
    }
#pragma unroll
    for (int j = 0; j < 4; j++) {
      accX[0][j] = __builtin_amdgcn_mfma_f32_16x16x32_f16(ah0, bl[j], accX[0][j], 0, 0, 0);
      accX[1][j] = __builtin_amdgcn_mfma_f32_16x16x32_f16(ah1, bl[j], accX[1][j], 0, 0, 0);
    }
#pragma unroll
    for (int j = 0; j < 4; j++) {
      accX[0][j] = __builtin_amdgcn_mfma_f32_16x16x32_f16(al0, bh[j], accX[0][j], 0, 0, 0);
      accX[1][j] = __builtin_amdgcn_mfma_f32_16x16x32_f16(al1, bh[j], accX[1][j], 0, 0, 0);
    }

    // rotate
    ah0 = nah0; al0 = nal0; ah1 = nah1; al1 = nal1;
#pragma unroll
    for (int j = 0; j < 4; j++) { bh[j] = nbh[j]; bl[j] = nbl[j]; }
  }

#pragma unroll
  for (int i = 0; i < 2; i++)
#pragma unroll
    for (int j = 0; j < 4; j++) {
      const int colg = n0 + j * 16 + l15;
      const float bb = bias[colg];
#pragma unroll
      for (int r = 0; r < 4; r++) {
        const int mm = m0 + i * 16 + quad * 4 + r;
        C[(long)mm * E_ + colg] =
            accH[i][j][r] + accX[i][j][r] * (1.0f / 4096.0f) + bb;
      }
    }
}

// ---------------------------------------------------------------------------
// mfma_gemm v8 (out-projection): bf16 3-term. A = attn in TILED fp32
// fragment layout (coalesced lane-linear loads, split in-register);
// B pre-split bf16 TILED. permC write. 256 blocks.
// ---------------------------------------------------------------------------
__global__ __launch_bounds__(256) void mfma_gemm(
    const float* __restrict__ A,
    const uint16_t* __restrict__ Bht, const uint16_t* __restrict__ Blt,
    const float* __restrict__ bias, float* __restrict__ C)
{
  const int wid = threadIdx.x >> 6, lane = threadIdx.x & 63;
  const int mb = blockIdx.x * 4 + wid;
  const int m0 = mb * 32;
  const int nb0 = blockIdx.y * 4;
  const int n0 = blockIdx.y * 64;
  const int l15 = lane & 15, quad = lane >> 4;

  const long aB = (long)mb * 16384 + lane * 8;   // fp32 elems, tiled
  long bB[4];
#pragma unroll
  for (int j = 0; j < 4; j++) bB[j] = (long)(nb0 + j) * 8192 + lane * 8;

  v4f acc[2][4] = {};
  for (int ks = 0; ks < 16; ks++) {
    const long a0 = aB + ks * 1024;     // half 0
    const long a1 = a0 + 512;           // half 1
    v8s ah0, al0, ah1, al1;
    split8(*(const float4*)(A + a0), *(const float4*)(A + a0 + 4), ah0, al0);
    split8(*(const float4*)(A + a1), *(const float4*)(A + a1 + 4), ah1, al1);
    v8s bh[4], bl[4];
#pragma unroll
    for (int j = 0; j < 4; j++) {
      bh[j] = *(const v8s*)(Bht + bB[j] + ks * 512);
      bl[j] = *(const v8s*)(Blt + bB[j] + ks * 512);
    }
#pragma unroll
    for (int j = 0; j < 4; j++) {
      acc[0][j] = __builtin_amdgcn_mfma_f32_16x16x32_bf16(ah0, bh[j], acc[0][j], 0, 0, 0);
      acc[1][j] = __builtin_amdgcn_mfma_f32_16x16x32_bf16(ah1, bh[j], acc[1][j], 0, 0, 0);
    }
#pragma unroll
    for (int j = 0; j < 4; j++) {
      acc[0][j] = __builtin_amdgcn_mfma_f32_16x16x32_bf16(ah0, bl[j], acc[0][j], 0, 0, 0);
      acc[1][j] = __builtin_amdgcn_mfma_f32_16x16x32_bf16(ah1, bl[j], acc[1][j], 0, 0, 0);
    }
#pragma unroll
    for (int j = 0; j < 4; j++) {
      acc[0][j] = __builtin_amdgcn_mfma_f32_16x16x32_bf16(al0, bh[j], acc[0][j], 0, 0, 0);
      acc[1][j] = __builtin_amdgcn_mfma_f32_16x16x32_bf16(al1, bh[j], acc[1][j], 0, 0, 0);
    }
  }

#pragma unroll
  for (int i = 0; i < 2; i++)
#pragma unroll
    for (int j = 0; j < 4; j++) {
      const int colg = n0 + j * 16 + l15;
      const float bb = bias[colg];
#pragma unroll
      for (int r = 0; r < 4; r++) {
        const int mm = m0 + i * 16 + quad * 4 + r;
        const int crow = (mm & (T_ - 1)) * B_ + (mm >> 11);
        C[(long)crow * E_ + colg] = acc[i][j][r] + bb;
      }
    }
}

// ---------------------------------------------------------------------------
// hash_mfma v4: LSH hash as 3-term fp16 MFMA GEMM + in-register argmax.
// grid (256, 4): y = src*2 + r; 256 thr; wave does 32 rows (2x4 tiles, K=64).
// ---------------------------------------------------------------------------
__global__ __launch_bounds__(256) void hash_mfma(
    const float* __restrict__ Q, const float* __restrict__ K,
    const uint16_t* __restrict__ Lwh, const uint16_t* __restrict__ Lwl,
    const float* __restrict__ lshb,
    int* __restrict__ qh, int* __restrict__ kh,
    int* __restrict__ qcnt, int* __restrict__ kcnt)
{
  const int comb = blockIdx.y;               // 0..3
  const int src = comb >> 1, r = comb & 1;
  const float* X = src ? K : Q;
  int* outh = src ? kh : qh;
  int* cnt  = src ? kcnt : qcnt;

  const int wid = threadIdx.x >> 6, lane = threadIdx.x & 63;
  const int m0 = (blockIdx.x * 4 + wid) * 32;  // head-row base (32 rows/wave)
  const int l15 = lane & 15, quad = lane >> 4;

  v8h bh[4][2], bl[4][2];
#pragma unroll
  for (int n = 0; n < 4; n++)
#pragma unroll
    for (int k = 0; k < 2; k++) {
      const int o = r * (DH_ * DH_) + (n * 16 + l15) * DH_ + k * 32 + quad * 8;
      bh[n][k] = *(const v8h*)(Lwh + o);
      bl[n][k] = *(const v8h*)(Lwl + o);
    }

  v4f accH[2][4] = {};
  v4f accX[2][4] = {};
#pragma unroll
  for (int k = 0; k < 2; k++) {
    const long a0 = (long)(m0 + l15) * DH_ + k * 32 + quad * 8;
    const long a1 = a0 + 16L * DH_;
    v8h ah0, al0, ah1, al1;
    split2h8(*(const float4*)(X + a0), *(const float4*)(X + a0 + 4), ah0, al0);
    split2h8(*(const float4*)(X + a1), *(const float4*)(X + a1 + 4), ah1, al1);
#pragma unroll
    for (int n = 0; n < 4; n++) {
      accH[0][n] = __builtin_amdgcn_mfma_f32_16x16x32_f16(ah0, bh[n][k], accH[0][n], 0, 0, 0);
      accH[1][n] = __builtin_amdgcn_mfma_f32_16x16x32_f16(ah1, bh[n][k], accH[1][n], 0, 0, 0);
      accX[0][n] = __builtin_amdgcn_mfma_f32_16x16x32_f16(ah0, bl[n][k], accX[0][n], 0, 0, 0);
      accX[1][n] = __builtin_amdgcn_mfma_f32_16x16x32_f16(ah1, bl[n][k], accX[1][n], 0, 0, 0);
      accX[0][n] = __builtin_amdgcn_mfma_f32_16x16x32_f16(al0, bh[n][k], accX[0][n], 0, 0, 0);
      accX[1][n] = __builtin_amdgcn_mfma_f32_16x16x32_f16(al1, bh[n][k], accX[1][n], 0, 0, 0);
    }
  }

  float bb[4];
#pragma unroll
  for (int n = 0; n < 4; n++) bb[n] = lshb[r * DH_ + n * 16 + l15];

#pragma unroll
  for (int i = 0; i < 2; i++)
#pragma unroll
    for (int reg = 0; reg < 4; reg++) {
      float bv = -INFINITY; int bi = 0x7fffffff;
#pragma unroll
      for (int n = 0; n < 4; n++) {
        const float v = accH[i][n][reg] + accX[i][n][reg] * (1.0f / 4096.0f)
                        + bb[n];
        const int idx = n * 16 + l15;
        if (v > bv || (v == bv && idx < bi)) { bv = v; bi = idx; }
      }
#pragma unroll
      for (int d = 8; d >= 1; d >>= 1) {
        const float ov = __shfl_xor(bv, d);
        const int oi = __shfl_xor(bi, d);
        if (ov > bv || (ov == bv && oi < bi)) { bv = ov; bi = oi; }
      }
      if (l15 == 0) {
        const int hr = m0 + i * 16 + quad * 4 + reg;
        const int p = hr >> 3, hh = hr & 7;
        const int bt = p >> 11, t = p & (T_ - 1);
        const int seg = r * 16 + bt * H_ + hh;
        outh[seg * T_ + t] = bi;
        if (bi < NBUCKET) atomicAdd(&cnt[seg * NBUCKET + bi], 1);
      }
    }
}

// ---------------------------------------------------------------------------
// Scan v4: 2 blocks x 1024 threads; one thread per (seg,bucket).
// Task emission now 32-query chunks (nt = ceil(c/32)).
// ---------------------------------------------------------------------------
__global__ __launch_bounds__(1024) void scan_kernel(
    const int* __restrict__ kcnt, int* __restrict__ koff,
    int* __restrict__ kcur,
    const int* __restrict__ qcnt, int* __restrict__ qoff,
    int* __restrict__ qcur,
    int* __restrict__ ntasks, int* __restrict__ tasks)
{
  const int tid = threadIdx.x;          // 0..1023
  const int isq = blockIdx.x;           // 0 = k-side, 1 = q-side
  const int seg = tid >> 5;             // 0..31
  const int b   = tid & 31;             // bucket
  const int* cnt = isq ? qcnt : kcnt;
  int* off = isq ? qoff : koff;
  int* cur = isq ? qcur : kcur;

  const int c = cnt[seg * NBUCKET + b];

  int s = c;
#pragma unroll
  for (int d = 1; d < 32; d <<= 1) {
    const int t = __shfl_up(s, d, 32);
    if (b >= d) s += t;
  }
  const int excl = s - c;
  off[seg * (NBUCKET + 1) + b] = excl;
  cur[seg * NBUCKET + b] = excl;
  if (b == 31) off[seg * (NBUCKET + 1) + NBUCKET] = s;

  if (isq) {
    const int nt = (c + 31) >> 5;       // 32-query tasks
    const int lane = tid & 63;
    int ws = nt;
#pragma unroll
    for (int d = 1; d < 64; d <<= 1) {
      const int t = __shfl_up(ws, d, 64);
      if (lane >= d) ws += t;
    }
    const int wtotal = __shfl(ws, 63, 64);
    int base = 0;
    if (lane == 63 && wtotal > 0) base = atomicAdd(ntasks, wtotal);
    base = __shfl(base, 63, 64);
    const int my = base + ws - nt;
    for (int i = 0; i < nt; i++)
      tasks[my + i] = (seg << 16) | (b << 8) | i;
  }
}

__global__ __launch_bounds__(256) void scatter2_kernel(
    const int* __restrict__ kh, const int* __restrict__ qh,
    int* __restrict__ kcur, int* __restrict__ qcur,
    int* __restrict__ klist, int* __restrict__ qlist)
{
  const int idx = blockIdx.x * 256 + threadIdx.x;
  const int y = blockIdx.y;
  const int* hsh = y ? qh : kh;
  int* cur = y ? qcur : kcur;
  int* list = y ? qlist : klist;
  const int v = hsh[idx];
  if (v < NBUCKET) {
    const int seg = idx >> 11;
    const int pos = atomicAdd(&cur[seg * NBUCKET + v], 1);
    list[seg * T_ + pos] = idx & (T_ - 1);
  }
}

// ---------------------------------------------------------------------------
// attn_task v10: MFMA bucket attention, 32-QUERY tasks (halves scattered
// K/V re-reads vs 16-q). Two 16-row tiles throughout. Epilogue writes attn
// in TILED fp32 A-fragment layout. LDS ~26KB (6 blocks/CU).
// ---------------------------------------------------------------------------
__global__ __launch_bounds__(256) void attn_task(
    const float* __restrict__ Q, const float* __restrict__ K,
    const float* __restrict__ V,
    const int* __restrict__ qlist, const int* __restrict__ qoff,
    const int* __restrict__ klist, const int* __restrict__ koff,
    const int* __restrict__ tasks, const int* __restrict__ ntasks,
    float* __restrict__ attn)
{
  __shared__ __align__(16) float Plds[32][68];
  __shared__ __align__(16) float Vts[64][68];
  __shared__ float larr[32];

  if ((int)blockIdx.x >= *ntasks) return;
  const int tk = tasks[blockIdx.x];
  const int seg = tk >> 16, bucket = (tk >> 8) & 255, qt = tk & 255;
  const int ctx = seg & 15;
  const int b = ctx >> 3, h = ctx & 7;

  const int qlo = qoff[seg * (NBUCKET + 1) + bucket] + qt * 32;
  const int nqt = min(32, qoff[seg * (NBUCKET + 1) + bucket + 1] - qlo);
  const int klo = koff[seg * (NBUCKET + 1) + bucket];
  const int nk  = koff[seg * (NBUCKET + 1) + bucket + 1] - klo;
  if (nk == 0) return;

  const int tid = threadIdx.x;
  const int wid = tid >> 6, lane = tid & 63;
  const int l15 = lane & 15, quad = lane >> 4;
  const int r0 = tid >> 4, c4 = tid & 15;   // V-staging coords

  const float* Qb = Q + ((long)b * T_) * E_ + h * DH_;
  const float* Kb = K + ((long)b * T_) * E_ + h * DH_;
  const float* Vb = V + ((long)b * T_) * E_ + h * DH_;
  const int* ql = qlist + seg * T_;
  const int* kl = klist + seg * T_;

  if (tid < 32) larr[tid] = 0.f;

  // Q A-fragments: 2 row-tiles; row q = i*16+l15 (clamped), k = quad*8 (+32/ks)
  v8s qfh[2][2], qfl[2][2];
#pragma unroll
  for (int i = 0; i < 2; i++) {
    const long qrow = (long)ql[qlo + min(i * 16 + l15, nqt - 1)] * E_;
#pragma unroll
    for (int ks = 0; ks < 2; ks++) {
      const float4 a = *(const float4*)(Qb + qrow + ks * 32 + quad * 8);
      const float4 c = *(const float4*)(Qb + qrow + ks * 32 + quad * 8 + 4);
      split8(a, c, qfh[i][ks], qfl[i][ks]);
    }
  }
  __syncthreads();          // larr init visible before first atomics

  v4f oacc[2] = {{0.f, 0.f, 0.f, 0.f}, {0.f, 0.f, 0.f, 0.f}};

  for (int kt = 0; kt < nk; kt += 64) {
    // --- V tile loads into registers (latency hides under QK MFMAs) ---
    float4 vreg[4];
#pragma unroll
    for (int it = 0; it < 4; it++) {
      const int key = kt + it * 16 + r0;
      const long krow = (long)kl[klo + min(key, nk - 1)] * E_;
      vreg[it] = *(const float4*)(Vb + krow + c4 * 4);
    }

    // --- QK^T: this wave's 16 keys (cols = l15) x 32 queries, bf16 3-term ---
    const int keyg = kt + wid * 16 + l15;
    const long krow = (long)kl[klo + min(keyg, nk - 1)] * E_;
    v4f sacc[2] = {{0.f, 0.f, 0.f, 0.f}, {0.f, 0.f, 0.f, 0.f}};
#pragma unroll
    for (int ks = 0; ks < 2; ks++) {
      const float4 a = *(const float4*)(Kb + krow + ks * 32 + quad * 8);
      const float4 c = *(const float4*)(Kb + krow + ks * 32 + quad * 8 + 4);
      v8s kfh, kfl;
      split8(a, c, kfh, kfl);
#pragma unroll
      for (int i = 0; i < 2; i++) {
        sacc[i] = __builtin_amdgcn_mfma_f32_16x16x32_bf16(qfh[i][ks], kfh, sacc[i], 0, 0, 0);
        sacc[i] = __builtin_amdgcn_mfma_f32_16x16x32_bf16(qfh[i][ks], kfl, sacc[i], 0, 0, 0);
        sacc[i] = __builtin_amdgcn_mfma_f32_16x16x32_bf16(qfl[i][ks], kfh, sacc[i], 0, 0, 0);
      }
    }

    const bool kvalid = keyg < nk;
#pragma unroll
    for (int i = 0; i < 2; i++) {
      const float p0 = kvalid ? __expf(sacc[i][0] * 0.125f) : 0.f;
      const float p1 = kvalid ? __expf(sacc[i][1] * 0.125f) : 0.f;
      const float p2 = kvalid ? __expf(sacc[i][2] * 0.125f) : 0.f;
      const float p3 = kvalid ? __expf(sacc[i][3] * 0.125f) : 0.f;

      float rs0 = p0, rs1 = p1, rs2 = p2, rs3 = p3;
#pragma unroll
      for (int d = 1; d < 16; d <<= 1) {
        rs0 += __shfl_xor(rs0, d);
        rs1 += __shfl_xor(rs1, d);
        rs2 += __shfl_xor(rs2, d);
        rs3 += __shfl_xor(rs3, d);
      }
      if (l15 == 0) {
        atomicAdd(&larr[i * 16 + quad * 4 + 0], rs0);
        atomicAdd(&larr[i * 16 + quad * 4 + 1], rs1);
        atomicAdd(&larr[i * 16 + quad * 4 + 2], rs2);
        atomicAdd(&larr[i * 16 + quad * 4 + 3], rs3);
      }
      Plds[i * 16 + quad * 4 + 0][wid * 16 + l15] = p0;
      Plds[i * 16 + quad * 4 + 1][wid * 16 + l15] = p1;
      Plds[i * 16 + quad * 4 + 2][wid * 16 + l15] = p2;
      Plds[i * 16 + quad * 4 + 3][wid * 16 + l15] = p3;
    }

    // --- Vt transpose store (waits on vreg loads here, post-MFMA) ---
#pragma unroll
    for (int it = 0; it < 4; it++) {
      const int row = it * 16 + r0;
      Vts[c4 * 4 + 0][row] = vreg[it].x;
      Vts[c4 * 4 + 1][row] = vreg[it].y;
      Vts[c4 * 4 + 2][row] = vreg[it].z;
      Vts[c4 * 4 + 3][row] = vreg[it].w;
    }
    __syncthreads();

    // --- PV: this wave's 16 dims (cols = wid*16+l15), keys as K-dim ---
#pragma unroll
    for (int ks = 0; ks < 2; ks++) {
      const float4 va = *(const float4*)&Vts[wid * 16 + l15][ks * 32 + quad * 8];
      const float4 vb = *(const float4*)&Vts[wid * 16 + l15][ks * 32 + quad * 8 + 4];
      v8s vfh, vfl;
      split8(va, vb, vfh, vfl);
#pragma unroll
      for (int i = 0; i < 2; i++) {
        const float4 pa = *(const float4*)&Plds[i * 16 + l15][ks * 32 + quad * 8];
        const float4 pb = *(const float4*)&Plds[i * 16 + l15][ks * 32 + quad * 8 + 4];
        v8s pah, pal;
        split8(pa, pb, pah, pal);
        oacc[i] = __builtin_amdgcn_mfma_f32_16x16x32_bf16(pah, vfh, oacc[i], 0, 0, 0);
        oacc[i] = __builtin_amdgcn_mfma_f32_16x16x32_bf16(pah, vfl, oacc[i], 0, 0, 0);
        oacc[i] = __builtin_amdgcn_mfma_f32_16x16x32_bf16(pal, vfh, oacc[i], 0, 0, 0);
      }
    }
    __syncthreads();
  }

  // epilogue: oacc[i] row q=i*16+quad*4+r, col d=wid*16+l15; TILED attn write:
  // p = b*T+t, kd = h*64+d
  const int kd = h * DH_ + wid * 16 + l15;
  const int kpart = (kd >> 5) * 2 * 512 + ((kd >> 3) & 3) * 16 * 8 + (kd & 7);
#pragma unroll
  for (int i = 0; i < 2; i++)
#pragma unroll
    for (int r = 0; r < 4; r++) {
      const int q = i * 16 + quad * 4 + r;
      if (q < nqt) {
        const float inv = 0.5f / larr[q];
        const int t = ql[qlo + q];
        const int p = b * T_ + t;
        const long off = (long)(p >> 5) * 16384 + ((p >> 4) & 1) * 512
                         + (p & 15) * 8 + kpart;
        atomicAdd(attn + off, oacc[i][r] * inv);
      }
    }
}

// ---------------------------------------------------------------------------
extern "C" void kernel_launch(void* const* d_in, const int* in_sizes, int n_in,
                              void* d_out, int out_size, void* d_ws, size_t ws_size,
                              hipStream_t stream) {
  const float* query = (const float*)d_in[0];
  const float* key   = (const float*)d_in[1];
  const float* value = (const float*)d_in[2];
  const float* Wq = (const float*)d_in[3];
  const float* bq = (const float*)d_in[4];
  const float* Wk = (const float*)d_in[5];
  const float* bk = (const float*)d_in[6];
  const float* Wv = (const float*)d_in[7];
  const float* bv = (const float*)d_in[8];
  const float* Wo = (const float*)d_in[9];
  const float* bo = (const float*)d_in[10];
  const float* lshW = (const float*)d_in[11];
  const float* lshb = (const float*)d_in[12];

  const size_t MSZ = (size_t)M_ * E_;
  const size_t WSZ = (size_t)E_ * E_;
  float* Q    = (float*)d_ws;
  float* K    = Q + MSZ;
  float* V    = K + MSZ;
  float* attn = V + MSZ;
  int* qh     = (int*)(attn + MSZ);
  int* kh     = qh + NSEG * T_;
  int* klist  = kh + NSEG * T_;
  int* qlist  = klist + NSEG * T_;
  int* kcnt   = qlist + NSEG * T_;       // start of zeroed region
  int* qcnt   = kcnt + NSEG * NBUCKET;
  int* ntasks = qcnt + NSEG * NBUCKET;   // end of zeroed region
  int* kcur   = ntasks + 1;
  int* qcur   = kcur + NSEG * NBUCKET;
  int* koff   = qcur + NSEG * NBUCKET;
  int* qoff   = koff + NSEG * (NBUCKET + 1);
  int* tasks  = qoff + NSEG * (NBUCKET + 1);
  uint16_t* Woh = (uint16_t*)(((uintptr_t)(tasks + MAXTASK) + 15) & ~(uintptr_t)15);
  uint16_t* Wol = Woh + WSZ;
  uint16_t* Wqh = Wol + WSZ;
  uint16_t* Wql = Wqh + WSZ;
  uint16_t* Wkh = Wql + WSZ;
  uint16_t* Wkl = Wkh + WSZ;
  uint16_t* Wvh = Wkl + WSZ;
  uint16_t* Wvl = Wvh + WSZ;
  uint16_t* Xqh = Wvl + WSZ;
  uint16_t* Xql = Xqh + MSZ;
  uint16_t* Xkh = Xql + MSZ;
  uint16_t* Xkl = Xkh + MSZ;
  uint16_t* Xvh = Xkl + MSZ;
  uint16_t* Xvl = Xvh + MSZ;
  uint16_t* Lwh = Xvl + MSZ;
  uint16_t* Lwl = Lwh + (size_t)NROUND * DH_ * DH_;

  prep_kernel<<<dim3(1921), 256, 0, stream>>>(
      query, key, value, Wq, Wk, Wv, Wo, lshW,
      Xqh, Xql, Xkh, Xkl, Xvh, Xvl,
      Wqh, Wql, Wkh, Wkl, Wvh, Wvl, Woh, Wol,
      Lwh, Lwl, attn, kcnt);
  proj_mfma<<<dim3(M_ / 128, E_ / 64, 3), 256, 0, stream>>>(
      Xqh, Xql, Xkh, Xkl, Xvh, Xvl,
      Wqh, Wql, Wkh, Wkl, Wvh, Wvl,
      bq, bk, bv, Q, K, V);
  hash_mfma<<<dim3(M_ * H_ / 128, 4), 256, 0, stream>>>(
      Q, K, Lwh, Lwl, lshb, qh, kh, qcnt, kcnt);
  scan_kernel<<<dim3(2), 1024, 0, stream>>>(kcnt, koff, kcur, qcnt, qoff, qcur,
                                            ntasks, tasks);
  scatter2_kernel<<<dim3(NSEG * T_ / 256, 2), 256, 0, stream>>>(
      kh, qh, kcur, qcur, klist, qlist);
  attn_task<<<dim3(MAXTASK), 256, 0, stream>>>(
      Q, K, V, qlist, qoff, klist, koff, tasks, ntasks, attn);
  mfma_gemm<<<dim3(M_ / 128, E_ / 64), 256, 0, stream>>>(
      attn, Woh, Wol, bo, (float*)d_out);
}

// Round 11
// 210.027 us; speedup vs baseline: 1.0337x; 1.0337x over previous
//
#include <hip/hip_runtime.h>
#include <stdint.h>
#include <math.h>

// ReformerAttention on MI355X — fp32 I/O. B=2,T=2048,E=512,H=8,Dh=64,
// 2 hash rounds, buckets<32 attend.
// Projection row p = logical (b'=p>>11, t'=p&2047); gathers input row (b=p&1, t=p>>1).
//
// 7 launches:
//   prep (fp16 2-way split of q/k/v/Wq/Wk/Wv + bf16 hi/lo Wo, TILED dest-linear;
//         + lshW split + zero attn/cnt)
//   -> proj_mfma (fused Q,K,V projections, fp16 3-term, tiled operands)
//   -> hash_mfma (LDS-staged A, +hist) -> scan(+tasks, 16-q) -> scatter2
//   -> attn_task (MFMA, 16-query tasks; writes attn in TILED fp32 layout)
//   -> mfma_gemm(out, tiled-A + tiled-B, perm)
//
// r10 lesson (regression, +5.4us): 32-q tasks halved task parallelism ->
//   tail/imbalance + lower occupancy outweighed gather savings. attn_task is
//   latency/parallelism-bound. REVERTED to 16-q (r9 config, 211.8us).
//   Line model scope note: it predicts per-instruction address-divergence
//   cost (proj r6, outproj r8, prep r9 — 3-for-3), NOT total redundant bytes.
// r11 change: hash_mfma A-loads had the 16-lines/instr disease (lane=row at
//   256B stride). v5 stages each block's 128 contiguous head-rows (32KB)
//   coalesced into LDS xs[128][68] (pad 68 -> 2-way bank conflict = free),
//   fragments read from LDS. Same values/argmax/histogram. LDS 34.8KB ->
//   4 blocks/CU = exactly this grid's residency need.
// Tiled layouts (elem offsets, fp16/bf16/fp32 units):
//   A[mb][ks][half]: ((mb*32 + ks*2 + half)*64 + lane)*8,
//     row=mb*32+half*16+(lane&15), k=ks*32+(lane>>4)*8
//   B[nb][ks]: ((nb*16 + ks)*64 + lane)*8, col=nb*16+(lane&15), k=ks*32+(lane>>4)*8
// Q,K precision: x = h + l/4096 fp16 split (verified r2-r10, argmax-safe).
// scan v3 (r3): shfl prefix scans, ONE atomicAdd per wave, 16-q tasks.
// attn v8 (r7/r8): MFMA wave-split bucket attention, tiled attn output.

#define T_ 2048
#define E_ 512
#define H_ 8
#define DH_ 64
#define B_ 2
#define M_ 4096
#define NROUND 2
#define NBUCKET 32
#define NSEG 32
#define MAXTASK 5120

typedef short v8s __attribute__((ext_vector_type(8)));
typedef _Float16 v8h __attribute__((ext_vector_type(8)));
typedef float v4f __attribute__((ext_vector_type(4)));

__device__ __forceinline__ float bf2f(uint16_t u) {
  union { uint32_t i; float f; } v; v.i = ((uint32_t)u) << 16; return v.f;
}
__device__ __forceinline__ uint16_t f2bf(float f) {
  union { float fv; uint32_t i; } v; v.fv = f;
  uint32_t x = v.i;
  x += 0x7fffu + ((x >> 16) & 1u);   // RN-even
  return (uint16_t)(x >> 16);
}
__device__ __forceinline__ void split8(const float4 a, const float4 b,
                                       v8s& h, v8s& l) {
  const float x[8] = {a.x, a.y, a.z, a.w, b.x, b.y, b.z, b.w};
#pragma unroll
  for (int j = 0; j < 8; j++) {
    const uint16_t hh = f2bf(x[j]);
    h[j] = (short)hh;
    l[j] = (short)f2bf(x[j] - bf2f(hh));
  }
}
// 2-way fp16 split with scaled residual: x = h + l*2^-12, no fp16 subnormals.
__device__ __forceinline__ void split2h8(const float4 a, const float4 b,
                                         v8h& h, v8h& l) {
  const float x[8] = {a.x, a.y, a.z, a.w, b.x, b.y, b.z, b.w};
#pragma unroll
  for (int j = 0; j < 8; j++) {
    const float xv = x[j];
    const _Float16 hh = (fabsf(xv) < 6.1035156e-5f) ? (_Float16)0.0f
                                                    : (_Float16)xv;
    const float r = xv - (float)hh;          // exact (Sterbenz / hh==0)
    h[j] = hh;
    l[j] = (_Float16)(r * 4096.0f);
  }
}

// ---------------------------------------------------------------------------
// prep v9: staging into tiled fragment layouts, DEST-LINEAR (stores are
// contiguous 1KB/instr; strided reads get L1/L2 reuse within a block).
//   blocks [0,384)     : q/k/v fp16 split, gathered, tiled (block per mb)
//   blocks [384,896)   : Wq/Wk/Wv fp16 + Wo bf16 splits, tiled
//   blocks [896,1920)  : zero attn
//   block  1920        : zero cnt region + lshW fp16 split
// ---------------------------------------------------------------------------
__global__ __launch_bounds__(256) void prep_kernel(
    const float* __restrict__ Xq, const float* __restrict__ Xk,
    const float* __restrict__ Xv,
    const float* __restrict__ Wq, const float* __restrict__ Wk,
    const float* __restrict__ Wv, const float* __restrict__ Wo,
    const float* __restrict__ lshW,
    uint16_t* __restrict__ Xqh, uint16_t* __restrict__ Xql,
    uint16_t* __restrict__ Xkh, uint16_t* __restrict__ Xkl,
    uint16_t* __restrict__ Xvh, uint16_t* __restrict__ Xvl,
    uint16_t* __restrict__ Wqh, uint16_t* __restrict__ Wql,
    uint16_t* __restrict__ Wkh, uint16_t* __restrict__ Wkl,
    uint16_t* __restrict__ Wvh, uint16_t* __restrict__ Wvl,
    uint16_t* __restrict__ Woh, uint16_t* __restrict__ Wol,
    uint16_t* __restrict__ Lwh, uint16_t* __restrict__ Lwl,
    float* __restrict__ attn, int* __restrict__ cnt)
{
  const int bid = blockIdx.x;
  const int tid = threadIdx.x;

  if (bid < 384) {                       // q/k/v fp16 split (gathered, tiled)
    const int sel = bid >> 7;            // 0=q,1=k,2=v
    const int mb  = bid & 127;           // 32-row block
    const float* X = (sel == 0) ? Xq : (sel == 1) ? Xk : Xv;
    uint16_t* H = (sel == 0) ? Xqh : (sel == 1) ? Xkh : Xvh;
    uint16_t* L = (sel == 0) ? Xql : (sel == 1) ? Xkl : Xvl;
#pragma unroll
    for (int it = 0; it < 8; it++) {
      const int g = it * 256 + tid;      // chunk within mb: [0,2048)
      const int f = g >> 6;              // frag 0..31 (ks*2+half)
      const int lane = g & 63;
      const int ks = f >> 1, half = f & 1;
      const int p = mb * 32 + half * 16 + (lane & 15);
      const int k = ks * 32 + (lane >> 4) * 8;
      const long src = ((long)(p & 1) * T_ + (p >> 1)) * E_ + k;
      const float4 a = *(const float4*)(X + src);
      const float4 b = *(const float4*)(X + src + 4);
      v8h h, l;
      split2h8(a, b, h, l);
      const long dst = (long)mb * 16384 + (long)g * 8;
      *(v8h*)(H + dst) = h;
      *(v8h*)(L + dst) = l;
    }
    return;
  }

  if (bid < 896) {                       // weight splits, tiled, dest-linear
    const int wsel = (bid - 384) >> 7;   // 0=Wq,1=Wk,2=Wv,3=Wo
    const int g2 = ((bid - 384) & 127) * 256 + tid;   // chunk [0,32768)
    const int f = g2 >> 6;               // frag 0..511 (nb*16+ks)
    const int lane = g2 & 63;
    const int nb = f >> 4, ks = f & 15;
    const int n = nb * 16 + (lane & 15);
    const int k = ks * 32 + (lane >> 4) * 8;
    const long src = (long)n * E_ + k;
    const long dst = (long)g2 * 8;
    if (wsel < 3) {
      const float* S = (wsel == 0) ? Wq : (wsel == 1) ? Wk : Wv;
      const float4 a = *(const float4*)(S + src);
      const float4 b = *(const float4*)(S + src + 4);
      v8h h, l;
      split2h8(a, b, h, l);
      uint16_t* H = (wsel == 0) ? Wqh : (wsel == 1) ? Wkh : Wvh;
      uint16_t* L = (wsel == 0) ? Wql : (wsel == 1) ? Wkl : Wvl;
      *(v8h*)(H + dst) = h;
      *(v8h*)(L + dst) = l;
    } else {
      const float4 a = *(const float4*)(Wo + src);
      const float4 b = *(const float4*)(Wo + src + 4);
      v8s h, l;
      split8(a, b, h, l);
      *(v8s*)(Woh + dst) = h;
      *(v8s*)(Wol + dst) = l;
    }
    return;
  }

  if (bid < 1920) {                      // zero attn: 1024 blocks x 512 float4
    float4* a4 = (float4*)attn;
    const int g = (bid - 896) * 512 + tid * 2;
    a4[g] = make_float4(0.f, 0.f, 0.f, 0.f);
    a4[g + 1] = make_float4(0.f, 0.f, 0.f, 0.f);
    return;
  }

  for (int i = tid; i < 2 * NSEG * NBUCKET + 1; i += 256) cnt[i] = 0;
  for (int i = tid; i < NROUND * DH_ * DH_; i += 256) {  // lshW fp16 split
    const float xv = lshW[i];
    const _Float16 hh = (fabsf(xv) < 6.1035156e-5f) ? (_Float16)0.0f
                                                    : (_Float16)xv;
    const float r = xv - (float)hh;
    *(_Float16*)(Lwh + i) = hh;
    *(_Float16*)(Lwl + i) = (_Float16)(r * 4096.0f);
  }
}

// ---------------------------------------------------------------------------
// proj_mfma v6: fused Q/K/V projections, fp16 3-term, TILED operands.
// grid (32, 8, 3) = 768 blocks; 2x4 16x16 tiles/wave (32x64). Every operand
// load is lane-linear 16B (coalesced 1KB/instr). Register double-buffered.
// ---------------------------------------------------------------------------
__global__ __launch_bounds__(256) void proj_mfma(
    const uint16_t* __restrict__ Aqh, const uint16_t* __restrict__ Aql,
    const uint16_t* __restrict__ Akh, const uint16_t* __restrict__ Akl,
    const uint16_t* __restrict__ Avh, const uint16_t* __restrict__ Avl,
    const uint16_t* __restrict__ Bqh, const uint16_t* __restrict__ Bql,
    const uint16_t* __restrict__ Bkh, const uint16_t* __restrict__ Bkl,
    const uint16_t* __restrict__ Bvh, const uint16_t* __restrict__ Bvl,
    const float* __restrict__ bq, const float* __restrict__ bk,
    const float* __restrict__ bv,
    float* __restrict__ Qo, float* __restrict__ Ko, float* __restrict__ Vo)
{
  const uint16_t *Ah, *Al, *Bh, *Bl;
  const float* bias; float* C;
  if (blockIdx.z == 0)      { Ah = Aqh; Al = Aql; Bh = Bqh; Bl = Bql; bias = bq; C = Qo; }
  else if (blockIdx.z == 1) { Ah = Akh; Al = Akl; Bh = Bkh; Bl = Bkl; bias = bk; C = Ko; }
  else                      { Ah = Avh; Al = Avl; Bh = Bvh; Bl = Bvl; bias = bv; C = Vo; }

  const int wid = threadIdx.x >> 6, lane = threadIdx.x & 63;
  const int mb = blockIdx.x * 4 + wid;        // 32-row block
  const int nb0 = blockIdx.y * 4;             // first 16-col block
  const int m0 = mb * 32, n0 = blockIdx.y * 64;
  const int l15 = lane & 15, quad = lane >> 4;

  // tiled bases (fp16 elem units); frag strides: A ks*1024, half 512; B ks*512
  const long aB = (long)mb * 16384 + lane * 8;
  long bB[4];
#pragma unroll
  for (int j = 0; j < 4; j++) bB[j] = (long)(nb0 + j) * 8192 + lane * 8;

  v4f accH[2][4] = {};
  v4f accX[2][4] = {};

  // prologue: ks = 0
  v8h ah0 = *(const v8h*)(Ah + aB);
  v8h ah1 = *(const v8h*)(Ah + aB + 512);
  v8h al0 = *(const v8h*)(Al + aB);
  v8h al1 = *(const v8h*)(Al + aB + 512);
  v8h bh[4], bl[4];
#pragma unroll
  for (int j = 0; j < 4; j++) {
    bh[j] = *(const v8h*)(Bh + bB[j]);
    bl[j] = *(const v8h*)(Bl + bB[j]);
  }

  for (int ks = 0; ks < 16; ks++) {
    const int kn = (ks + 1) & 15;   // wraps on last iter; values unused
    const v8h nah0 = *(const v8h*)(Ah + aB + kn * 1024);
    const v8h nah1 = *(const v8h*)(Ah + aB + kn * 1024 + 512);
    const v8h nal0 = *(const v8h*)(Al + aB + kn * 1024);
    const v8h nal1 = *(const v8h*)(Al + aB + kn * 1024 + 512);
    v8h nbh[4], nbl[4];
#pragma unroll
    for (int j = 0; j < 4; j++) {
      nbh[j] = *(const v8h*)(Bh + bB[j] + kn * 512);
      nbl[j] = *(const v8h*)(Bl + bB[j] + kn * 512);
    }

    // 24 MFMAs: hh -> accH; h*l' and l'*h -> accX (carries 2^12 scale)
#pragma unroll
    for (int j = 0; j < 4; j++) {
      accH[0][j] = __builtin_amdgcn_mfma_f32_16x16x32_f16(ah0, bh[j], accH[0][j], 0, 0, 0);
      accH[1][j] = __builtin_amdgcn_mfma_f32_16x16x32_f16(ah1, bh[j], accH[1][j], 0, 0, 0);
    }
#pragma unroll
    for (int j = 0; j < 4; j++) {
      accX[0][j] = __builtin_amdgcn_mfma_f32_16x16x32_f16(ah0, bl[j], accX[0][j], 0, 0, 0);
      accX[1][j] = __builtin_amdgcn_mfma_f32_16x16x32_f16(ah1, bl[j], accX[1][j], 0, 0, 0);
    }
#pragma unroll
    for (int j = 0; j < 4; j++) {
      accX[0][j] = __builtin_amdgcn_mfma_f32_16x16x32_f16(al0, bh[j], accX[0][j], 0, 0, 0);
      accX[1][j] = __builtin_amdgcn_mfma_f32_16x16x32_f16(al1, bh[j], accX[1][j], 0, 0, 0);
    }

    // rotate
    ah0 = nah0; al0 = nal0; ah1 = nah1; al1 = nal1;
#pragma unroll
    for (int j = 0; j < 4; j++) { bh[j] = nbh[j]; bl[j] = nbl[j]; }
  }

#pragma unroll
  for (int i = 0; i < 2; i++)
#pragma unroll
    for (int j = 0; j < 4; j++) {
      const int colg = n0 + j * 16 + l15;
      const float bb = bias[colg];
#pragma unroll
      for (int r = 0; r < 4; r++) {
        const int mm = m0 + i * 16 + quad * 4 + r;
        C[(long)mm * E_ + colg] =
            accH[i][j][r] + accX[i][j][r] * (1.0f / 4096.0f) + bb;
      }
    }
}

// ---------------------------------------------------------------------------
// mfma_gemm v8 (out-projection): bf16 3-term. A = attn in TILED fp32
// fragment layout (coalesced lane-linear loads, split in-register);
// B pre-split bf16 TILED. permC write. 256 blocks.
// ---------------------------------------------------------------------------
__global__ __launch_bounds__(256) void mfma_gemm(
    const float* __restrict__ A,
    const uint16_t* __restrict__ Bht, const uint16_t* __restrict__ Blt,
    const float* __restrict__ bias, float* __restrict__ C)
{
  const int wid = threadIdx.x >> 6, lane = threadIdx.x & 63;
  const int mb = blockIdx.x * 4 + wid;
  const int m0 = mb * 32;
  const int nb0 = blockIdx.y * 4;
  const int n0 = blockIdx.y * 64;
  const int l15 = lane & 15, quad = lane >> 4;

  const long aB = (long)mb * 16384 + lane * 8;   // fp32 elems, tiled
  long bB[4];
#pragma unroll
  for (int j = 0; j < 4; j++) bB[j] = (long)(nb0 + j) * 8192 + lane * 8;

  v4f acc[2][4] = {};
  for (int ks = 0; ks < 16; ks++) {
    const long a0 = aB + ks * 1024;     // half 0
    const long a1 = a0 + 512;           // half 1
    v8s ah0, al0, ah1, al1;
    split8(*(const float4*)(A + a0), *(const float4*)(A + a0 + 4), ah0, al0);
    split8(*(const float4*)(A + a1), *(const float4*)(A + a1 + 4), ah1, al1);
    v8s bh[4], bl[4];
#pragma unroll
    for (int j = 0; j < 4; j++) {
      bh[j] = *(const v8s*)(Bht + bB[j] + ks * 512);
      bl[j] = *(const v8s*)(Blt + bB[j] + ks * 512);
    }
#pragma unroll
    for (int j = 0; j < 4; j++) {
      acc[0][j] = __builtin_amdgcn_mfma_f32_16x16x32_bf16(ah0, bh[j], acc[0][j], 0, 0, 0);
      acc[1][j] = __builtin_amdgcn_mfma_f32_16x16x32_bf16(ah1, bh[j], acc[1][j], 0, 0, 0);
    }
#pragma unroll
    for (int j = 0; j < 4; j++) {
      acc[0][j] = __builtin_amdgcn_mfma_f32_16x16x32_bf16(ah0, bl[j], acc[0][j], 0, 0, 0);
      acc[1][j] = __builtin_amdgcn_mfma_f32_16x16x32_bf16(ah1, bl[j], acc[1][j], 0, 0, 0);
    }
#pragma unroll
    for (int j = 0; j < 4; j++) {
      acc[0][j] = __builtin_amdgcn_mfma_f32_16x16x32_bf16(al0, bh[j], acc[0][j], 0, 0, 0);
      acc[1][j] = __builtin_amdgcn_mfma_f32_16x16x32_bf16(al1, bh[j], acc[1][j], 0, 0, 0);
    }
  }

#pragma unroll
  for (int i = 0; i < 2; i++)
#pragma unroll
    for (int j = 0; j < 4; j++) {
      const int colg = n0 + j * 16 + l15;
      const float bb = bias[colg];
#pragma unroll
      for (int r = 0; r < 4; r++) {
        const int mm = m0 + i * 16 + quad * 4 + r;
        const int crow = (mm & (T_ - 1)) * B_ + (mm >> 11);
        C[(long)crow * E_ + colg] = acc[i][j][r] + bb;
      }
    }
}

// ---------------------------------------------------------------------------
// hash_mfma v5: LSH hash as 3-term fp16 MFMA GEMM + in-register argmax.
// A now LDS-STAGED: each block stages its 128 contiguous head-rows (32KB)
// coalesced into xs[128][68] (pad 68 -> 2-way bank conflict, free), then
// fragments read from LDS (was: 16-scattered-lines/instr global loads).
// grid (256, 4): y = src*2 + r; 256 thr; wave does 32 rows (2x4 tiles, K=64).
// ---------------------------------------------------------------------------
__global__ __launch_bounds__(256) void hash_mfma(
    const float* __restrict__ Q, const float* __restrict__ K,
    const uint16_t* __restrict__ Lwh, const uint16_t* __restrict__ Lwl,
    const float* __restrict__ lshb,
    int* __restrict__ qh, int* __restrict__ kh,
    int* __restrict__ qcnt, int* __restrict__ kcnt)
{
  __shared__ __align__(16) float xs[128][68];

  const int comb = blockIdx.y;               // 0..3
  const int src = comb >> 1, r = comb & 1;
  const float* X = src ? K : Q;
  int* outh = src ? kh : qh;
  int* cnt  = src ? kcnt : qcnt;

  const int tid = threadIdx.x;
  const int wid = tid >> 6, lane = tid & 63;
  const int blockBase = blockIdx.x * 128;    // head-row base for block
  const int m0 = blockBase + wid * 32;       // head-row base for wave
  const int l15 = lane & 15, quad = lane >> 4;

  // coalesced stage: 128 rows x 64 floats = 2048 float4, 256 thr x 8 iters
  const float4* src4 = (const float4*)(X + (long)blockBase * DH_);
#pragma unroll
  for (int it = 0; it < 8; it++) {
    const int g = it * 256 + tid;
    const int row = g >> 4, c4 = g & 15;
    *(float4*)&xs[row][c4 * 4] = src4[g];
  }

  v8h bh[4][2], bl[4][2];
#pragma unroll
  for (int n = 0; n < 4; n++)
#pragma unroll
    for (int k = 0; k < 2; k++) {
      const int o = r * (DH_ * DH_) + (n * 16 + l15) * DH_ + k * 32 + quad * 8;
      bh[n][k] = *(const v8h*)(Lwh + o);
      bl[n][k] = *(const v8h*)(Lwl + o);
    }
  __syncthreads();

  v4f accH[2][4] = {};
  v4f accX[2][4] = {};
#pragma unroll
  for (int k = 0; k < 2; k++) {
#pragma unroll
    for (int i = 0; i < 2; i++) {
      const int lrow = wid * 32 + i * 16 + l15;
      const float4 a = *(const float4*)&xs[lrow][k * 32 + quad * 8];
      const float4 c = *(const float4*)&xs[lrow][k * 32 + quad * 8 + 4];
      v8h ah, al;
      split2h8(a, c, ah, al);
#pragma unroll
      for (int n = 0; n < 4; n++) {
        accH[i][n] = __builtin_amdgcn_mfma_f32_16x16x32_f16(ah, bh[n][k], accH[i][n], 0, 0, 0);
        accX[i][n] = __builtin_amdgcn_mfma_f32_16x16x32_f16(ah, bl[n][k], accX[i][n], 0, 0, 0);
        accX[i][n] = __builtin_amdgcn_mfma_f32_16x16x32_f16(al, bh[n][k], accX[i][n], 0, 0, 0);
      }
    }
  }

  float bb[4];
#pragma unroll
  for (int n = 0; n < 4; n++) bb[n] = lshb[r * DH_ + n * 16 + l15];

#pragma unroll
  for (int i = 0; i < 2; i++)
#pragma unroll
    for (int reg = 0; reg < 4; reg++) {
      float bv = -INFINITY; int bi = 0x7fffffff;
#pragma unroll
      for (int n = 0; n < 4; n++) {
        const float v = accH[i][n][reg] + accX[i][n][reg] * (1.0f / 4096.0f)
                        + bb[n];
        const int idx = n * 16 + l15;
        if (v > bv || (v == bv && idx < bi)) { bv = v; bi = idx; }
      }
#pragma unroll
      for (int d = 8; d >= 1; d >>= 1) {
        const float ov = __shfl_xor(bv, d);
        const int oi = __shfl_xor(bi, d);
        if (ov > bv || (ov == bv && oi < bi)) { bv = ov; bi = oi; }
      }
      if (l15 == 0) {
        const int hr = m0 + i * 16 + quad * 4 + reg;
        const int p = hr >> 3, hh = hr & 7;
        const int bt = p >> 11, t = p & (T_ - 1);
        const int seg = r * 16 + bt * H_ + hh;
        outh[seg * T_ + t] = bi;
        if (bi < NBUCKET) atomicAdd(&cnt[seg * NBUCKET + bi], 1);
      }
    }
}

// ---------------------------------------------------------------------------
// Scan v3: 2 blocks x 1024 threads; one thread per (seg,bucket).
// 16-query task emission (r10 showed 32-q loses parallelism).
// ---------------------------------------------------------------------------
__global__ __launch_bounds__(1024) void scan_kernel(
    const int* __restrict__ kcnt, int* __restrict__ koff,
    int* __restrict__ kcur,
    const int* __restrict__ qcnt, int* __restrict__ qoff,
    int* __restrict__ qcur,
    int* __restrict__ ntasks, int* __restrict__ tasks)
{
  const int tid = threadIdx.x;          // 0..1023
  const int isq = blockIdx.x;           // 0 = k-side, 1 = q-side
  const int seg = tid >> 5;             // 0..31
  const int b   = tid & 31;             // bucket
  const int* cnt = isq ? qcnt : kcnt;
  int* off = isq ? qoff : koff;
  int* cur = isq ? qcur : kcur;

  const int c = cnt[seg * NBUCKET + b];

  int s = c;
#pragma unroll
  for (int d = 1; d < 32; d <<= 1) {
    const int t = __shfl_up(s, d, 32);
    if (b >= d) s += t;
  }
  const int excl = s - c;
  off[seg * (NBUCKET + 1) + b] = excl;
  cur[seg * NBUCKET + b] = excl;
  if (b == 31) off[seg * (NBUCKET + 1) + NBUCKET] = s;

  if (isq) {
    const int nt = (c + 15) >> 4;       // 16-query tasks
    const int lane = tid & 63;
    int ws = nt;
#pragma unroll
    for (int d = 1; d < 64; d <<= 1) {
      const int t = __shfl_up(ws, d, 64);
      if (lane >= d) ws += t;
    }
    const int wtotal = __shfl(ws, 63, 64);
    int base = 0;
    if (lane == 63 && wtotal > 0) base = atomicAdd(ntasks, wtotal);
    base = __shfl(base, 63, 64);
    const int my = base + ws - nt;
    for (int i = 0; i < nt; i++)
      tasks[my + i] = (seg << 16) | (b << 8) | i;
  }
}

__global__ __launch_bounds__(256) void scatter2_kernel(
    const int* __restrict__ kh, const int* __restrict__ qh,
    int* __restrict__ kcur, int* __restrict__ qcur,
    int* __restrict__ klist, int* __restrict__ qlist)
{
  const int idx = blockIdx.x * 256 + threadIdx.x;
  const int y = blockIdx.y;
  const int* hsh = y ? qh : kh;
  int* cur = y ? qcur : kcur;
  int* list = y ? qlist : klist;
  const int v = hsh[idx];
  if (v < NBUCKET) {
    const int seg = idx >> 11;
    const int pos = atomicAdd(&cur[seg * NBUCKET + v], 1);
    list[seg * T_ + pos] = idx & (T_ - 1);
  }
}

// ---------------------------------------------------------------------------
// attn_task v8 (reverted r9 config): MFMA bucket attention, 16-query tasks;
// epilogue writes attn in the TILED fp32 A-fragment layout.
// ---------------------------------------------------------------------------
__global__ __launch_bounds__(256) void attn_task(
    const float* __restrict__ Q, const float* __restrict__ K,
    const float* __restrict__ V,
    const int* __restrict__ qlist, const int* __restrict__ qoff,
    const int* __restrict__ klist, const int* __restrict__ koff,
    const int* __restrict__ tasks, const int* __restrict__ ntasks,
    float* __restrict__ attn)
{
  __shared__ __align__(16) float Plds[16][68];
  __shared__ __align__(16) float Vts[64][68];
  __shared__ float larr[16];

  if ((int)blockIdx.x >= *ntasks) return;
  const int tk = tasks[blockIdx.x];
  const int seg = tk >> 16, bucket = (tk >> 8) & 255, qt = tk & 255;
  const int ctx = seg & 15;
  const int b = ctx >> 3, h = ctx & 7;

  const int qlo = qoff[seg * (NBUCKET + 1) + bucket] + qt * 16;
  const int nqt = min(16, qoff[seg * (NBUCKET + 1) + bucket + 1] - qlo);
  const int klo = koff[seg * (NBUCKET + 1) + bucket];
  const int nk  = koff[seg * (NBUCKET + 1) + bucket + 1] - klo;
  if (nk == 0) return;

  const int tid = threadIdx.x;
  const int wid = tid >> 6, lane = tid & 63;
  const int l15 = lane & 15, quad = lane >> 4;
  const int r0 = tid >> 4, c4 = tid & 15;   // V-staging coords

  const float* Qb = Q + ((long)b * T_) * E_ + h * DH_;
  const float* Kb = K + ((long)b * T_) * E_ + h * DH_;
  const float* Vb = V + ((long)b * T_) * E_ + h * DH_;
  const int* ql = qlist + seg * T_;
  const int* kl = klist + seg * T_;

  if (tid < 16) larr[tid] = 0.f;

  // Q A-fragments: row=q=l15 (clamped), k=dim quad*8 (+32 per ks)
  const long qrow = (long)ql[qlo + min(l15, nqt - 1)] * E_;
  v8s qfh[2], qfl[2];
#pragma unroll
  for (int ks = 0; ks < 2; ks++) {
    const float4 a = *(const float4*)(Qb + qrow + ks * 32 + quad * 8);
    const float4 c = *(const float4*)(Qb + qrow + ks * 32 + quad * 8 + 4);
    split8(a, c, qfh[ks], qfl[ks]);
  }
  __syncthreads();          // larr init visible before first atomics

  v4f oacc = {0.f, 0.f, 0.f, 0.f};

  for (int kt = 0; kt < nk; kt += 64) {
    // --- V tile loads into registers (latency hides under QK MFMAs) ---
    float4 vreg[4];
#pragma unroll
    for (int it = 0; it < 4; it++) {
      const int key = kt + it * 16 + r0;
      const long krow = (long)kl[klo + min(key, nk - 1)] * E_;
      vreg[it] = *(const float4*)(Vb + krow + c4 * 4);
    }

    // --- QK^T: this wave's 16 keys (cols = l15), bf16 3-term ---
    const int keyg = kt + wid * 16 + l15;
    const long krow = (long)kl[klo + min(keyg, nk - 1)] * E_;
    v4f sacc = {0.f, 0.f, 0.f, 0.f};
#pragma unroll
    for (int ks = 0; ks < 2; ks++) {
      const float4 a = *(const float4*)(Kb + krow + ks * 32 + quad * 8);
      const float4 c = *(const float4*)(Kb + krow + ks * 32 + quad * 8 + 4);
      v8s kfh, kfl;
      split8(a, c, kfh, kfl);
      sacc = __builtin_amdgcn_mfma_f32_16x16x32_bf16(qfh[ks], kfh, sacc, 0, 0, 0);
      sacc = __builtin_amdgcn_mfma_f32_16x16x32_bf16(qfh[ks], kfl, sacc, 0, 0, 0);
      sacc = __builtin_amdgcn_mfma_f32_16x16x32_bf16(qfl[ks], kfh, sacc, 0, 0, 0);
    }

    const bool kvalid = keyg < nk;
    const float p0 = kvalid ? __expf(sacc[0] * 0.125f) : 0.f;
    const float p1 = kvalid ? __expf(sacc[1] * 0.125f) : 0.f;
    const float p2 = kvalid ? __expf(sacc[2] * 0.125f) : 0.f;
    const float p3 = kvalid ? __expf(sacc[3] * 0.125f) : 0.f;

    float rs0 = p0, rs1 = p1, rs2 = p2, rs3 = p3;
#pragma unroll
    for (int d = 1; d < 16; d <<= 1) {
      rs0 += __shfl_xor(rs0, d);
      rs1 += __shfl_xor(rs1, d);
      rs2 += __shfl_xor(rs2, d);
      rs3 += __shfl_xor(rs3, d);
    }
    if (l15 == 0) {
      atomicAdd(&larr[quad * 4 + 0], rs0);
      atomicAdd(&larr[quad * 4 + 1], rs1);
      atomicAdd(&larr[quad * 4 + 2], rs2);
      atomicAdd(&larr[quad * 4 + 3], rs3);
    }
    Plds[quad * 4 + 0][wid * 16 + l15] = p0;
    Plds[quad * 4 + 1][wid * 16 + l15] = p1;
    Plds[quad * 4 + 2][wid * 16 + l15] = p2;
    Plds[quad * 4 + 3][wid * 16 + l15] = p3;

    // --- Vt transpose store (waits on vreg loads here, post-MFMA) ---
#pragma unroll
    for (int it = 0; it < 4; it++) {
      const int row = it * 16 + r0;
      Vts[c4 * 4 + 0][row] = vreg[it].x;
      Vts[c4 * 4 + 1][row] = vreg[it].y;
      Vts[c4 * 4 + 2][row] = vreg[it].z;
      Vts[c4 * 4 + 3][row] = vreg[it].w;
    }
    __syncthreads();

    // --- PV: this wave's 16 dims (cols = wid*16+l15), keys as K-dim ---
#pragma unroll
    for (int ks = 0; ks < 2; ks++) {
      const float4 pa = *(const float4*)&Plds[l15][ks * 32 + quad * 8];
      const float4 pb = *(const float4*)&Plds[l15][ks * 32 + quad * 8 + 4];
      v8s pah, pal;
      split8(pa, pb, pah, pal);
      const float4 va = *(const float4*)&Vts[wid * 16 + l15][ks * 32 + quad * 8];
      const float4 vb = *(const float4*)&Vts[wid * 16 + l15][ks * 32 + quad * 8 + 4];
      v8s vfh, vfl;
      split8(va, vb, vfh, vfl);
      oacc = __builtin_amdgcn_mfma_f32_16x16x32_bf16(pah, vfh, oacc, 0, 0, 0);
      oacc = __builtin_amdgcn_mfma_f32_16x16x32_bf16(pah, vfl, oacc, 0, 0, 0);
      oacc = __builtin_amdgcn_mfma_f32_16x16x32_bf16(pal, vfh, oacc, 0, 0, 0);
    }
    __syncthreads();
  }

  // epilogue: oacc row q=quad*4+r, col d=wid*16+l15; write TILED attn:
  // p = b*T+t (row), kd = h*64+d (col)
  const int kd = h * DH_ + wid * 16 + l15;
  const int kpart = (kd >> 5) * 2 * 512 + ((kd >> 3) & 3) * 16 * 8 + (kd & 7);
#pragma unroll
  for (int r = 0; r < 4; r++) {
    const int q = quad * 4 + r;
    if (q < nqt) {
      const float inv = 0.5f / larr[q];
      const int t = ql[qlo + q];
      const int p = b * T_ + t;
      const long off = (long)(p >> 5) * 16384 + ((p >> 4) & 1) * 512
                       + (p & 15) * 8 + kpart;
      atomicAdd(attn + off, oacc[r] * inv);
    }
  }
}

// ---------------------------------------------------------------------------
extern "C" void kernel_launch(void* const* d_in, const int* in_sizes, int n_in,
                              void* d_out, int out_size, void* d_ws, size_t ws_size,
                              hipStream_t stream) {
  const float* query = (const float*)d_in[0];
  const float* key   = (const float*)d_in[1];
  const float* value = (const float*)d_in[2];
  const float* Wq = (const float*)d_in[3];
  const float* bq = (const float*)d_in[4];
  const float* Wk = (const float*)d_in[5];
  const float* bk = (const float*)d_in[6];
  const float* Wv = (const float*)d_in[7];
  const float* bv = (const float*)d_in[8];
  const float* Wo = (const float*)d_in[9];
  const float* bo = (const float*)d_in[10];
  const float* lshW = (const float*)d_in[11];
  const float* lshb = (const float*)d_in[12];

  const size_t MSZ = (size_t)M_ * E_;
  const size_t WSZ = (size_t)E_ * E_;
  float* Q    = (float*)d_ws;
  float* K    = Q + MSZ;
  float* V    = K + MSZ;
  float* attn = V + MSZ;
  int* qh     = (int*)(attn + MSZ);
  int* kh     = qh + NSEG * T_;
  int* klist  = kh + NSEG * T_;
  int* qlist  = klist + NSEG * T_;
  int* kcnt   = qlist + NSEG * T_;       // start of zeroed region
  int* qcnt   = kcnt + NSEG * NBUCKET;
  int* ntasks = qcnt + NSEG * NBUCKET;   // end of zeroed region
  int* kcur   = ntasks + 1;
  int* qcur   = kcur + NSEG * NBUCKET;
  int* koff   = qcur + NSEG * NBUCKET;
  int* qoff   = koff + NSEG * (NBUCKET + 1);
  int* tasks  = qoff + NSEG * (NBUCKET + 1);
  uint16_t* Woh = (uint16_t*)(((uintptr_t)(tasks + MAXTASK) + 15) & ~(uintptr_t)15);
  uint16_t* Wol = Woh + WSZ;
  uint16_t* Wqh = Wol + WSZ;
  uint16_t* Wql = Wqh + WSZ;
  uint16_t* Wkh = Wql + WSZ;
  uint16_t* Wkl = Wkh + WSZ;
  uint16_t* Wvh = Wkl + WSZ;
  uint16_t* Wvl = Wvh + WSZ;
  uint16_t* Xqh = Wvl + WSZ;
  uint16_t* Xql = Xqh + MSZ;
  uint16_t* Xkh = Xql + MSZ;
  uint16_t* Xkl = Xkh + MSZ;
  uint16_t* Xvh = Xkl + MSZ;
  uint16_t* Xvl = Xvh + MSZ;
  uint16_t* Lwh = Xvl + MSZ;
  uint16_t* Lwl = Lwh + (size_t)NROUND * DH_ * DH_;

  prep_kernel<<<dim3(1921), 256, 0, stream>>>(
      query, key, value, Wq, Wk, Wv, Wo, lshW,
      Xqh, Xql, Xkh, Xkl, Xvh, Xvl,
      Wqh, Wql, Wkh, Wkl, Wvh, Wvl, Woh, Wol,
      Lwh, Lwl, attn, kcnt);
  proj_mfma<<<dim3(M_ / 128, E_ / 64, 3), 256, 0, stream>>>(
      Xqh, Xql, Xkh, Xkl, Xvh, Xvl,
      Wqh, Wql, Wkh, Wkl, Wvh, Wvl,
      bq, bk, bv, Q, K, V);
  hash_mfma<<<dim3(M_ * H_ / 128, 4), 256, 0, stream>>>(
      Q, K, Lwh, Lwl, lshb, qh, kh, qcnt, kcnt);
  scan_kernel<<<dim3(2), 1024, 0, stream>>>(kcnt, koff, kcur, qcnt, qoff, qcur,
                                            ntasks, tasks);
  scatter2_kernel<<<dim3(NSEG * T_ / 256, 2), 256, 0, stream>>>(
      kh, qh, kcur, qcur, klist, qlist);
  attn_task<<<dim3(MAXTASK), 256, 0, stream>>>(
      Q, K, V, qlist, qoff, klist, koff, tasks, ntasks, attn);
  mfma_gemm<<<dim3(M_ / 128, E_ / 64), 256, 0, stream>>>(
      attn, Woh, Wol, bo, (float*)d_out);
}

// Round 13
// 209.795 us; speedup vs baseline: 1.0349x; 1.0011x over previous
//
#include <hip/hip_runtime.h>
#include <stdint.h>
#include <math.h>

// ReformerAttention on MI355X — fp32 I/O. B=2,T=2048,E=512,H=8,Dh=64,
// 2 hash rounds, buckets<32 attend.
// Projection row p = logical (b'=p>>11, t'=p&2047); gathers input row (b=p&1, t=p>>1).
//
// 7 launches:
//   prep (fp16 2-way split of q/k/v/Wq/Wk/Wv + bf16 hi/lo Wo, TILED dest-linear;
//         + lshW split + zero attn/cnt)
//   -> proj_mfma (fused Q,K,V projections, fp16 3-term, tiled operands)
//   -> hash_mfma (LDS-staged A, +hist) -> scan(+tasks, 16-q) -> scatter2
//   -> attn_task (MFMA, 16-q tasks, K-gather pipelined; TILED attn out)
//   -> mfma_gemm(out, tiled-A + tiled-B, perm)
//
// r11 result: 210.0us best. Top-5 all harness fills (2x ~44us). r10 lesson:
//   attn_task is latency/parallelism-bound; don't trade parallelism for
//   traffic. r12: pipeline attn_task's K-gather — current tile's raw K
//   float4s held in regs (prologue load), next tile's K issued right after
//   consumption so the scattered-gather latency (~600cy) drains under
//   softmax+stores+barriers+PV (~1500cy). +16 VGPR, no LDS/parallelism
//   change. V was already prefetched at tile top (hides under QK MFMAs).
//   (r12 bench was an infra failure — container died twice; resubmitted.)
// Tiled layouts (elem offsets, fp16/bf16/fp32 units):
//   A[mb][ks][half]: ((mb*32 + ks*2 + half)*64 + lane)*8,
//     row=mb*32+half*16+(lane&15), k=ks*32+(lane>>4)*8
//   B[nb][ks]: ((nb*16 + ks)*64 + lane)*8, col=nb*16+(lane&15), k=ks*32+(lane>>4)*8
// Q,K precision: x = h + l/4096 fp16 split (verified r2-r11, argmax-safe).
// scan v3 (r3): shfl prefix scans, ONE atomicAdd per wave, 16-q tasks.
// hash v5 (r11): LDS-staged A, 3-term fp16 MFMA + in-reg argmax.

#define T_ 2048
#define E_ 512
#define H_ 8
#define DH_ 64
#define B_ 2
#define M_ 4096
#define NROUND 2
#define NBUCKET 32
#define NSEG 32
#define MAXTASK 5120

typedef short v8s __attribute__((ext_vector_type(8)));
typedef _Float16 v8h __attribute__((ext_vector_type(8)));
typedef float v4f __attribute__((ext_vector_type(4)));

__device__ __forceinline__ float bf2f(uint16_t u) {
  union { uint32_t i; float f; } v; v.i = ((uint32_t)u) << 16; return v.f;
}
__device__ __forceinline__ uint16_t f2bf(float f) {
  union { float fv; uint32_t i; } v; v.fv = f;
  uint32_t x = v.i;
  x += 0x7fffu + ((x >> 16) & 1u);   // RN-even
  return (uint16_t)(x >> 16);
}
__device__ __forceinline__ void split8(const float4 a, const float4 b,
                                       v8s& h, v8s& l) {
  const float x[8] = {a.x, a.y, a.z, a.w, b.x, b.y, b.z, b.w};
#pragma unroll
  for (int j = 0; j < 8; j++) {
    const uint16_t hh = f2bf(x[j]);
    h[j] = (short)hh;
    l[j] = (short)f2bf(x[j] - bf2f(hh));
  }
}
// 2-way fp16 split with scaled residual: x = h + l*2^-12, no fp16 subnormals.
__device__ __forceinline__ void split2h8(const float4 a, const float4 b,
                                         v8h& h, v8h& l) {
  const float x[8] = {a.x, a.y, a.z, a.w, b.x, b.y, b.z, b.w};
#pragma unroll
  for (int j = 0; j < 8; j++) {
    const float xv = x[j];
    const _Float16 hh = (fabsf(xv) < 6.1035156e-5f) ? (_Float16)0.0f
                                                    : (_Float16)xv;
    const float r = xv - (float)hh;          // exact (Sterbenz / hh==0)
    h[j] = hh;
    l[j] = (_Float16)(r * 4096.0f);
  }
}

// ---------------------------------------------------------------------------
// prep v9: staging into tiled fragment layouts, DEST-LINEAR (stores are
// contiguous 1KB/instr; strided reads get L1/L2 reuse within a block).
//   blocks [0,384)     : q/k/v fp16 split, gathered, tiled (block per mb)
//   blocks [384,896)   : Wq/Wk/Wv fp16 + Wo bf16 splits, tiled
//   blocks [896,1920)  : zero attn
//   block  1920        : zero cnt region + lshW fp16 split
// ---------------------------------------------------------------------------
__global__ __launch_bounds__(256) void prep_kernel(
    const float* __restrict__ Xq, const float* __restrict__ Xk,
    const float* __restrict__ Xv,
    const float* __restrict__ Wq, const float* __restrict__ Wk,
    const float* __restrict__ Wv, const float* __restrict__ Wo,
    const float* __restrict__ lshW,
    uint16_t* __restrict__ Xqh, uint16_t* __restrict__ Xql,
    uint16_t* __restrict__ Xkh, uint16_t* __restrict__ Xkl,
    uint16_t* __restrict__ Xvh, uint16_t* __restrict__ Xvl,
    uint16_t* __restrict__ Wqh, uint16_t* __restrict__ Wql,
    uint16_t* __restrict__ Wkh, uint16_t* __restrict__ Wkl,
    uint16_t* __restrict__ Wvh, uint16_t* __restrict__ Wvl,
    uint16_t* __restrict__ Woh, uint16_t* __restrict__ Wol,
    uint16_t* __restrict__ Lwh, uint16_t* __restrict__ Lwl,
    float* __restrict__ attn, int* __restrict__ cnt)
{
  const int bid = blockIdx.x;
  const int tid = threadIdx.x;

  if (bid < 384) {                       // q/k/v fp16 split (gathered, tiled)
    const int sel = bid >> 7;            // 0=q,1=k,2=v
    const int mb  = bid & 127;           // 32-row block
    const float* X = (sel == 0) ? Xq : (sel == 1) ? Xk : Xv;
    uint16_t* H = (sel == 0) ? Xqh : (sel == 1) ? Xkh : Xvh;
    uint16_t* L = (sel == 0) ? Xql : (sel == 1) ? Xkl : Xvl;
#pragma unroll
    for (int it = 0; it < 8; it++) {
      const int g = it * 256 + tid;      // chunk within mb: [0,2048)
      const int f = g >> 6;              // frag 0..31 (ks*2+half)
      const int lane = g & 63;
      const int ks = f >> 1, half = f & 1;
      const int p = mb * 32 + half * 16 + (lane & 15);
      const int k = ks * 32 + (lane >> 4) * 8;
      const long src = ((long)(p & 1) * T_ + (p >> 1)) * E_ + k;
      const float4 a = *(const float4*)(X + src);
      const float4 b = *(const float4*)(X + src + 4);
      v8h h, l;
      split2h8(a, b, h, l);
      const long dst = (long)mb * 16384 + (long)g * 8;
      *(v8h*)(H + dst) = h;
      *(v8h*)(L + dst) = l;
    }
    return;
  }

  if (bid < 896) {                       // weight splits, tiled, dest-linear
    const int wsel = (bid - 384) >> 7;   // 0=Wq,1=Wk,2=Wv,3=Wo
    const int g2 = ((bid - 384) & 127) * 256 + tid;   // chunk [0,32768)
    const int f = g2 >> 6;               // frag 0..511 (nb*16+ks)
    const int lane = g2 & 63;
    const int nb = f >> 4, ks = f & 15;
    const int n = nb * 16 + (lane & 15);
    const int k = ks * 32 + (lane >> 4) * 8;
    const long src = (long)n * E_ + k;
    const long dst = (long)g2 * 8;
    if (wsel < 3) {
      const float* S = (wsel == 0) ? Wq : (wsel == 1) ? Wk : Wv;
      const float4 a = *(const float4*)(S + src);
      const float4 b = *(const float4*)(S + src + 4);
      v8h h, l;
      split2h8(a, b, h, l);
      uint16_t* H = (wsel == 0) ? Wqh : (wsel == 1) ? Wkh : Wvh;
      uint16_t* L = (wsel == 0) ? Wql : (wsel == 1) ? Wkl : Wvl;
      *(v8h*)(H + dst) = h;
      *(v8h*)(L + dst) = l;
    } else {
      const float4 a = *(const float4*)(Wo + src);
      const float4 b = *(const float4*)(Wo + src + 4);
      v8s h, l;
      split8(a, b, h, l);
      *(v8s*)(Woh + dst) = h;
      *(v8s*)(Wol + dst) = l;
    }
    return;
  }

  if (bid < 1920) {                      // zero attn: 1024 blocks x 512 float4
    float4* a4 = (float4*)attn;
    const int g = (bid - 896) * 512 + tid * 2;
    a4[g] = make_float4(0.f, 0.f, 0.f, 0.f);
    a4[g + 1] = make_float4(0.f, 0.f, 0.f, 0.f);
    return;
  }

  for (int i = tid; i < 2 * NSEG * NBUCKET + 1; i += 256) cnt[i] = 0;
  for (int i = tid; i < NROUND * DH_ * DH_; i += 256) {  // lshW fp16 split
    const float xv = lshW[i];
    const _Float16 hh = (fabsf(xv) < 6.1035156e-5f) ? (_Float16)0.0f
                                                    : (_Float16)xv;
    const float r = xv - (float)hh;
    *(_Float16*)(Lwh + i) = hh;
    *(_Float16*)(Lwl + i) = (_Float16)(r * 4096.0f);
  }
}

// ---------------------------------------------------------------------------
// proj_mfma v6: fused Q/K/V projections, fp16 3-term, TILED operands.
// grid (32, 8, 3) = 768 blocks; 2x4 16x16 tiles/wave (32x64). Every operand
// load is lane-linear 16B (coalesced 1KB/instr). Register double-buffered.
// ---------------------------------------------------------------------------
__global__ __launch_bounds__(256) void proj_mfma(
    const uint16_t* __restrict__ Aqh, const uint16_t* __restrict__ Aql,
    const uint16_t* __restrict__ Akh, const uint16_t* __restrict__ Akl,
    const uint16_t* __restrict__ Avh, const uint16_t* __restrict__ Avl,
    const uint16_t* __restrict__ Bqh, const uint16_t* __restrict__ Bql,
    const uint16_t* __restrict__ Bkh, const uint16_t* __restrict__ Bkl,
    const uint16_t* __restrict__ Bvh, const uint16_t* __restrict__ Bvl,
    const float* __restrict__ bq, const float* __restrict__ bk,
    const float* __restrict__ bv,
    float* __restrict__ Qo, float* __restrict__ Ko, float* __restrict__ Vo)
{
  const uint16_t *Ah, *Al, *Bh, *Bl;
  const float* bias; float* C;
  if (blockIdx.z == 0)      { Ah = Aqh; Al = Aql; Bh = Bqh; Bl = Bql; bias = bq; C = Qo; }
  else if (blockIdx.z == 1) { Ah = Akh; Al = Akl; Bh = Bkh; Bl = Bkl; bias = bk; C = Ko; }
  else                      { Ah = Avh; Al = Avl; Bh = Bvh; Bl = Bvl; bias = bv; C = Vo; }

  const int wid = threadIdx.x >> 6, lane = threadIdx.x & 63;
  const int mb = blockIdx.x * 4 + wid;        // 32-row block
  const int nb0 = blockIdx.y * 4;             // first 16-col block
  const int m0 = mb * 32, n0 = blockIdx.y * 64;
  const int l15 = lane & 15, quad = lane >> 4;

  // tiled bases (fp16 elem units); frag strides: A ks*1024, half 512; B ks*512
  const long aB = (long)mb * 16384 + lane * 8;
  long bB[4];
#pragma unroll
  for (int j = 0; j < 4; j++) bB[j] = (long)(nb0 + j) * 8192 + lane * 8;

  v4f accH[2][4] = {};
  v4f accX[2][4] = {};

  // prologue: ks = 0
  v8h ah0 = *(const v8h*)(Ah + aB);
  v8h ah1 = *(const v8h*)(Ah + aB + 512);
  v8h al0 = *(const v8h*)(Al + aB);
  v8h al1 = *(const v8h*)(Al + aB + 512);
  v8h bh[4], bl[4];
#pragma unroll
  for (int j = 0; j < 4; j++) {
    bh[j] = *(const v8h*)(Bh + bB[j]);
    bl[j] = *(const v8h*)(Bl + bB[j]);
  }

  for (int ks = 0; ks < 16; ks++) {
    const int kn = (ks + 1) & 15;   // wraps on last iter; values unused
    const v8h nah0 = *(const v8h*)(Ah + aB + kn * 1024);
    const v8h nah1 = *(const v8h*)(Ah + aB + kn * 1024 + 512);
    const v8h nal0 = *(const v8h*)(Al + aB + kn * 1024);
    const v8h nal1 = *(const v8h*)(Al + aB + kn * 1024 + 512);
    v8h nbh[4], nbl[4];
#pragma unroll
    for (int j = 0; j < 4; j++) {
      nbh[j] = *(const v8h*)(Bh + bB[j] + kn * 512);
      nbl[j] = *(const v8h*)(Bl + bB[j] + kn * 512);
    }

    // 24 MFMAs: hh -> accH; h*l' and l'*h -> accX (carries 2^12 scale)
#pragma unroll
    for (int j = 0; j < 4; j++) {
      accH[0][j] = __builtin_amdgcn_mfma_f32_16x16x32_f16(ah0, bh[j], accH[0][j], 0, 0, 0);
      accH[1][j] = __builtin_amdgcn_mfma_f32_16x16x32_f16(ah1, bh[j], accH[1][j], 0, 0, 0);
    }
#pragma unroll
    for (int j = 0; j < 4; j++) {
      accX[0][j] = __builtin_amdgcn_mfma_f32_16x16x32_f16(ah0, bl[j], accX[0][j], 0, 0, 0);
      accX[1][j] = __builtin_amdgcn_mfma_f32_16x16x32_f16(ah1, bl[j], accX[1][j], 0, 0, 0);
    }
#pragma unroll
    for (int j = 0; j < 4; j++) {
      accX[0][j] = __builtin_amdgcn_mfma_f32_16x16x32_f16(al0, bh[j], accX[0][j], 0, 0, 0);
      accX[1][j] = __builtin_amdgcn_mfma_f32_16x16x32_f16(al1, bh[j], accX[1][j], 0, 0, 0);
    }

    // rotate
    ah0 = nah0; al0 = nal0; ah1 = nah1; al1 = nal1;
#pragma unroll
    for (int j = 0; j < 4; j++) { bh[j] = nbh[j]; bl[j] = nbl[j]; }
  }

#pragma unroll
  for (int i = 0; i < 2; i++)
#pragma unroll
    for (int j = 0; j < 4; j++) {
      const int colg = n0 + j * 16 + l15;
      const float bb = bias[colg];
#pragma unroll
      for (int r = 0; r < 4; r++) {
        const int mm = m0 + i * 16 + quad * 4 + r;
        C[(long)mm * E_ + colg] =
            accH[i][j][r] + accX[i][j][r] * (1.0f / 4096.0f) + bb;
      }
    }
}

// ---------------------------------------------------------------------------
// mfma_gemm v8 (out-projection): bf16 3-term. A = attn in TILED fp32
// fragment layout (coalesced lane-linear loads, split in-register);
// B pre-split bf16 TILED. permC write. 256 blocks.
// ---------------------------------------------------------------------------
__global__ __launch_bounds__(256) void mfma_gemm(
    const float* __restrict__ A,
    const uint16_t* __restrict__ Bht, const uint16_t* __restrict__ Blt,
    const float* __restrict__ bias, float* __restrict__ C)
{
  const int wid = threadIdx.x >> 6, lane = threadIdx.x & 63;
  const int mb = blockIdx.x * 4 + wid;
  const int m0 = mb * 32;
  const int nb0 = blockIdx.y * 4;
  const int n0 = blockIdx.y * 64;
  const int l15 = lane & 15, quad = lane >> 4;

  const long aB = (long)mb * 16384 + lane * 8;   // fp32 elems, tiled
  long bB[4];
#pragma unroll
  for (int j = 0; j < 4; j++) bB[j] = (long)(nb0 + j) * 8192 + lane * 8;

  v4f acc[2][4] = {};
  for (int ks = 0; ks < 16; ks++) {
    const long a0 = aB + ks * 1024;     // half 0
    const long a1 = a0 + 512;           // half 1
    v8s ah0, al0, ah1, al1;
    split8(*(const float4*)(A + a0), *(const float4*)(A + a0 + 4), ah0, al0);
    split8(*(const float4*)(A + a1), *(const float4*)(A + a1 + 4), ah1, al1);
    v8s bh[4], bl[4];
#pragma unroll
    for (int j = 0; j < 4; j++) {
      bh[j] = *(const v8s*)(Bht + bB[j] + ks * 512);
      bl[j] = *(const v8s*)(Blt + bB[j] + ks * 512);
    }
#pragma unroll
    for (int j = 0; j < 4; j++) {
      acc[0][j] = __builtin_amdgcn_mfma_f32_16x16x32_bf16(ah0, bh[j], acc[0][j], 0, 0, 0);
      acc[1][j] = __builtin_amdgcn_mfma_f32_16x16x32_bf16(ah1, bh[j], acc[1][j], 0, 0, 0);
    }
#pragma unroll
    for (int j = 0; j < 4; j++) {
      acc[0][j] = __builtin_amdgcn_mfma_f32_16x16x32_bf16(ah0, bl[j], acc[0][j], 0, 0, 0);
      acc[1][j] = __builtin_amdgcn_mfma_f32_16x16x32_bf16(ah1, bl[j], acc[1][j], 0, 0, 0);
    }
#pragma unroll
    for (int j = 0; j < 4; j++) {
      acc[0][j] = __builtin_amdgcn_mfma_f32_16x16x32_bf16(al0, bh[j], acc[0][j], 0, 0, 0);
      acc[1][j] = __builtin_amdgcn_mfma_f32_16x16x32_bf16(al1, bh[j], acc[1][j], 0, 0, 0);
    }
  }

#pragma unroll
  for (int i = 0; i < 2; i++)
#pragma unroll
    for (int j = 0; j < 4; j++) {
      const int colg = n0 + j * 16 + l15;
      const float bb = bias[colg];
#pragma unroll
      for (int r = 0; r < 4; r++) {
        const int mm = m0 + i * 16 + quad * 4 + r;
        const int crow = (mm & (T_ - 1)) * B_ + (mm >> 11);
        C[(long)crow * E_ + colg] = acc[i][j][r] + bb;
      }
    }
}

// ---------------------------------------------------------------------------
// hash_mfma v5: LSH hash as 3-term fp16 MFMA GEMM + in-register argmax.
// A LDS-STAGED coalesced (xs[128][68], pad -> 2-way conflict = free).
// grid (256, 4): y = src*2 + r; 256 thr; wave does 32 rows (2x4 tiles, K=64).
// ---------------------------------------------------------------------------
__global__ __launch_bounds__(256) void hash_mfma(
    const float* __restrict__ Q, const float* __restrict__ K,
    const uint16_t* __restrict__ Lwh, const uint16_t* __restrict__ Lwl,
    const float* __restrict__ lshb,
    int* __restrict__ qh, int* __restrict__ kh,
    int* __restrict__ qcnt, int* __restrict__ kcnt)
{
  __shared__ __align__(16) float xs[128][68];

  const int comb = blockIdx.y;               // 0..3
  const int src = comb >> 1, r = comb & 1;
  const float* X = src ? K : Q;
  int* outh = src ? kh : qh;
  int* cnt  = src ? kcnt : qcnt;

  const int tid = threadIdx.x;
  const int wid = tid >> 6, lane = tid & 63;
  const int blockBase = blockIdx.x * 128;    // head-row base for block
  const int m0 = blockBase + wid * 32;       // head-row base for wave
  const int l15 = lane & 15, quad = lane >> 4;

  // coalesced stage: 128 rows x 64 floats = 2048 float4, 256 thr x 8 iters
  const float4* src4 = (const float4*)(X + (long)blockBase * DH_);
#pragma unroll
  for (int it = 0; it < 8; it++) {
    const int g = it * 256 + tid;
    const int row = g >> 4, c4 = g & 15;
    *(float4*)&xs[row][c4 * 4] = src4[g];
  }

  v8h bh[4][2], bl[4][2];
#pragma unroll
  for (int n = 0; n < 4; n++)
#pragma unroll
    for (int k = 0; k < 2; k++) {
      const int o = r * (DH_ * DH_) + (n * 16 + l15) * DH_ + k * 32 + quad * 8;
      bh[n][k] = *(const v8h*)(Lwh + o);
      bl[n][k] = *(const v8h*)(Lwl + o);
    }
  __syncthreads();

  v4f accH[2][4] = {};
  v4f accX[2][4] = {};
#pragma unroll
  for (int k = 0; k < 2; k++) {
#pragma unroll
    for (int i = 0; i < 2; i++) {
      const int lrow = wid * 32 + i * 16 + l15;
      const float4 a = *(const float4*)&xs[lrow][k * 32 + quad * 8];
      const float4 c = *(const float4*)&xs[lrow][k * 32 + quad * 8 + 4];
      v8h ah, al;
      split2h8(a, c, ah, al);
#pragma unroll
      for (int n = 0; n < 4; n++) {
        accH[i][n] = __builtin_amdgcn_mfma_f32_16x16x32_f16(ah, bh[n][k], accH[i][n], 0, 0, 0);
        accX[i][n] = __builtin_amdgcn_mfma_f32_16x16x32_f16(ah, bl[n][k], accX[i][n], 0, 0, 0);
        accX[i][n] = __builtin_amdgcn_mfma_f32_16x16x32_f16(al, bh[n][k], accX[i][n], 0, 0, 0);
      }
    }
  }

  float bb[4];
#pragma unroll
  for (int n = 0; n < 4; n++) bb[n] = lshb[r * DH_ + n * 16 + l15];

#pragma unroll
  for (int i = 0; i < 2; i++)
#pragma unroll
    for (int reg = 0; reg < 4; reg++) {
      float bv = -INFINITY; int bi = 0x7fffffff;
#pragma unroll
      for (int n = 0; n < 4; n++) {
        const float v = accH[i][n][reg] + accX[i][n][reg] * (1.0f / 4096.0f)
                        + bb[n];
        const int idx = n * 16 + l15;
        if (v > bv || (v == bv && idx < bi)) { bv = v; bi = idx; }
      }
#pragma unroll
      for (int d = 8; d >= 1; d >>= 1) {
        const float ov = __shfl_xor(bv, d);
        const int oi = __shfl_xor(bi, d);
        if (ov > bv || (ov == bv && oi < bi)) { bv = ov; bi = oi; }
      }
      if (l15 == 0) {
        const int hr = m0 + i * 16 + quad * 4 + reg;
        const int p = hr >> 3, hh = hr & 7;
        const int bt = p >> 11, t = p & (T_ - 1);
        const int seg = r * 16 + bt * H_ + hh;
        outh[seg * T_ + t] = bi;
        if (bi < NBUCKET) atomicAdd(&cnt[seg * NBUCKET + bi], 1);
      }
    }
}

// ---------------------------------------------------------------------------
// Scan v3: 2 blocks x 1024 threads; one thread per (seg,bucket).
// 16-query task emission (r10 showed 32-q loses parallelism).
// ---------------------------------------------------------------------------
__global__ __launch_bounds__(1024) void scan_kernel(
    const int* __restrict__ kcnt, int* __restrict__ koff,
    int* __restrict__ kcur,
    const int* __restrict__ qcnt, int* __restrict__ qoff,
    int* __restrict__ qcur,
    int* __restrict__ ntasks, int* __restrict__ tasks)
{
  const int tid = threadIdx.x;          // 0..1023
  const int isq = blockIdx.x;           // 0 = k-side, 1 = q-side
  const int seg = tid >> 5;             // 0..31
  const int b   = tid & 31;             // bucket
  const int* cnt = isq ? qcnt : kcnt;
  int* off = isq ? qoff : koff;
  int* cur = isq ? qcur : kcur;

  const int c = cnt[seg * NBUCKET + b];

  int s = c;
#pragma unroll
  for (int d = 1; d < 32; d <<= 1) {
    const int t = __shfl_up(s, d, 32);
    if (b >= d) s += t;
  }
  const int excl = s - c;
  off[seg * (NBUCKET + 1) + b] = excl;
  cur[seg * NBUCKET + b] = excl;
  if (b == 31) off[seg * (NBUCKET + 1) + NBUCKET] = s;

  if (isq) {
    const int nt = (c + 15) >> 4;       // 16-query tasks
    const int lane = tid & 63;
    int ws = nt;
#pragma unroll
    for (int d = 1; d < 64; d <<= 1) {
      const int t = __shfl_up(ws, d, 64);
      if (lane >= d) ws += t;
    }
    const int wtotal = __shfl(ws, 63, 64);
    int base = 0;
    if (lane == 63 && wtotal > 0) base = atomicAdd(ntasks, wtotal);
    base = __shfl(base, 63, 64);
    const int my = base + ws - nt;
    for (int i = 0; i < nt; i++)
      tasks[my + i] = (seg << 16) | (b << 8) | i;
  }
}

__global__ __launch_bounds__(256) void scatter2_kernel(
    const int* __restrict__ kh, const int* __restrict__ qh,
    int* __restrict__ kcur, int* __restrict__ qcur,
    int* __restrict__ klist, int* __restrict__ qlist)
{
  const int idx = blockIdx.x * 256 + threadIdx.x;
  const int y = blockIdx.y;
  const int* hsh = y ? qh : kh;
  int* cur = y ? qcur : kcur;
  int* list = y ? qlist : klist;
  const int v = hsh[idx];
  if (v < NBUCKET) {
    const int seg = idx >> 11;
    const int pos = atomicAdd(&cur[seg * NBUCKET + v], 1);
    list[seg * T_ + pos] = idx & (T_ - 1);
  }
}

// ---------------------------------------------------------------------------
// attn_task v12: MFMA bucket attention, 16-query tasks, K-gather PIPELINED:
// current tile's raw K float4s held in regs (prologue), next tile's K issued
// right after consumption — gather latency drains under softmax + stores +
// barriers + PV. Epilogue writes attn in TILED fp32 A-fragment layout.
// ---------------------------------------------------------------------------
__global__ __launch_bounds__(256) void attn_task(
    const float* __restrict__ Q, const float* __restrict__ K,
    const float* __restrict__ V,
    const int* __restrict__ qlist, const int* __restrict__ qoff,
    const int* __restrict__ klist, const int* __restrict__ koff,
    const int* __restrict__ tasks, const int* __restrict__ ntasks,
    float* __restrict__ attn)
{
  __shared__ __align__(16) float Plds[16][68];
  __shared__ __align__(16) float Vts[64][68];
  __shared__ float larr[16];

  if ((int)blockIdx.x >= *ntasks) return;
  const int tk = tasks[blockIdx.x];
  const int seg = tk >> 16, bucket = (tk >> 8) & 255, qt = tk & 255;
  const int ctx = seg & 15;
  const int b = ctx >> 3, h = ctx & 7;

  const int qlo = qoff[seg * (NBUCKET + 1) + bucket] + qt * 16;
  const int nqt = min(16, qoff[seg * (NBUCKET + 1) + bucket + 1] - qlo);
  const int klo = koff[seg * (NBUCKET + 1) + bucket];
  const int nk  = koff[seg * (NBUCKET + 1) + bucket + 1] - klo;
  if (nk == 0) return;

  const int tid = threadIdx.x;
  const int wid = tid >> 6, lane = tid & 63;
  const int l15 = lane & 15, quad = lane >> 4;
  const int r0 = tid >> 4, c4 = tid & 15;   // V-staging coords

  const float* Qb = Q + ((long)b * T_) * E_ + h * DH_;
  const float* Kb = K + ((long)b * T_) * E_ + h * DH_;
  const float* Vb = V + ((long)b * T_) * E_ + h * DH_;
  const int* ql = qlist + seg * T_;
  const int* kl = klist + seg * T_;

  if (tid < 16) larr[tid] = 0.f;

  // Q A-fragments: row=q=l15 (clamped), k=dim quad*8 (+32 per ks)
  const long qrow = (long)ql[qlo + min(l15, nqt - 1)] * E_;
  v8s qfh[2], qfl[2];
#pragma unroll
  for (int ks = 0; ks < 2; ks++) {
    const float4 a = *(const float4*)(Qb + qrow + ks * 32 + quad * 8);
    const float4 c = *(const float4*)(Qb + qrow + ks * 32 + quad * 8 + 4);
    split8(a, c, qfh[ks], qfl[ks]);
  }

  // K prologue: raw K float4s for tile 0 (this wave's 16 keys, cols=l15)
  float4 ka[2], kc[2];
  {
    const int key0 = wid * 16 + l15;
    const long kr0 = (long)kl[klo + min(key0, nk - 1)] * E_;
#pragma unroll
    for (int ks = 0; ks < 2; ks++) {
      ka[ks] = *(const float4*)(Kb + kr0 + ks * 32 + quad * 8);
      kc[ks] = *(const float4*)(Kb + kr0 + ks * 32 + quad * 8 + 4);
    }
  }
  __syncthreads();          // larr init visible before first atomics

  v4f oacc = {0.f, 0.f, 0.f, 0.f};

  for (int kt = 0; kt < nk; kt += 64) {
    // --- V tile loads into registers (latency hides under QK MFMAs) ---
    float4 vreg[4];
#pragma unroll
    for (int it = 0; it < 4; it++) {
      const int key = kt + it * 16 + r0;
      const long krow = (long)kl[klo + min(key, nk - 1)] * E_;
      vreg[it] = *(const float4*)(Vb + krow + c4 * 4);
    }

    // --- QK^T: consume pre-loaded K (bf16 3-term) ---
    const int keyg = kt + wid * 16 + l15;
    v4f sacc = {0.f, 0.f, 0.f, 0.f};
#pragma unroll
    for (int ks = 0; ks < 2; ks++) {
      v8s kfh, kfl;
      split8(ka[ks], kc[ks], kfh, kfl);
      sacc = __builtin_amdgcn_mfma_f32_16x16x32_bf16(qfh[ks], kfh, sacc, 0, 0, 0);
      sacc = __builtin_amdgcn_mfma_f32_16x16x32_bf16(qfh[ks], kfl, sacc, 0, 0, 0);
      sacc = __builtin_amdgcn_mfma_f32_16x16x32_bf16(qfl[ks], kfh, sacc, 0, 0, 0);
    }

    // --- prefetch next tile's K (in flight across softmax+stores+PV) ---
    {
      const int keyn = kt + 64 + wid * 16 + l15;
      const long krn = (long)kl[klo + min(keyn, nk - 1)] * E_;
#pragma unroll
      for (int ks = 0; ks < 2; ks++) {
        ka[ks] = *(const float4*)(Kb + krn + ks * 32 + quad * 8);
        kc[ks] = *(const float4*)(Kb + krn + ks * 32 + quad * 8 + 4);
      }
    }

    const bool kvalid = keyg < nk;
    const float p0 = kvalid ? __expf(sacc[0] * 0.125f) : 0.f;
    const float p1 = kvalid ? __expf(sacc[1] * 0.125f) : 0.f;
    const float p2 = kvalid ? __expf(sacc[2] * 0.125f) : 0.f;
    const float p3 = kvalid ? __expf(sacc[3] * 0.125f) : 0.f;

    float rs0 = p0, rs1 = p1, rs2 = p2, rs3 = p3;
#pragma unroll
    for (int d = 1; d < 16; d <<= 1) {
      rs0 += __shfl_xor(rs0, d);
      rs1 += __shfl_xor(rs1, d);
      rs2 += __shfl_xor(rs2, d);
      rs3 += __shfl_xor(rs3, d);
    }
    if (l15 == 0) {
      atomicAdd(&larr[quad * 4 + 0], rs0);
      atomicAdd(&larr[quad * 4 + 1], rs1);
      atomicAdd(&larr[quad * 4 + 2], rs2);
      atomicAdd(&larr[quad * 4 + 3], rs3);
    }
    Plds[quad * 4 + 0][wid * 16 + l15] = p0;
    Plds[quad * 4 + 1][wid * 16 + l15] = p1;
    Plds[quad * 4 + 2][wid * 16 + l15] = p2;
    Plds[quad * 4 + 3][wid * 16 + l15] = p3;

    // --- Vt transpose store (waits on vreg loads here, post-MFMA) ---
#pragma unroll
    for (int it = 0; it < 4; it++) {
      const int row = it * 16 + r0;
      Vts[c4 * 4 + 0][row] = vreg[it].x;
      Vts[c4 * 4 + 1][row] = vreg[it].y;
      Vts[c4 * 4 + 2][row] = vreg[it].z;
      Vts[c4 * 4 + 3][row] = vreg[it].w;
    }
    __syncthreads();

    // --- PV: this wave's 16 dims (cols = wid*16+l15), keys as K-dim ---
#pragma unroll
    for (int ks = 0; ks < 2; ks++) {
      const float4 pa = *(const float4*)&Plds[l15][ks * 32 + quad * 8];
      const float4 pb = *(const float4*)&Plds[l15][ks * 32 + quad * 8 + 4];
      v8s pah, pal;
      split8(pa, pb, pah, pal);
      const float4 va = *(const float4*)&Vts[wid * 16 + l15][ks * 32 + quad * 8];
      const float4 vb = *(const float4*)&Vts[wid * 16 + l15][ks * 32 + quad * 8 + 4];
      v8s vfh, vfl;
      split8(va, vb, vfh, vfl);
      oacc = __builtin_amdgcn_mfma_f32_16x16x32_bf16(pah, vfh, oacc, 0, 0, 0);
      oacc = __builtin_amdgcn_mfma_f32_16x16x32_bf16(pah, vfl, oacc, 0, 0, 0);
      oacc = __builtin_amdgcn_mfma_f32_16x16x32_bf16(pal, vfh, oacc, 0, 0, 0);
    }
    __syncthreads();
  }

  // epilogue: oacc row q=quad*4+r, col d=wid*16+l15; write TILED attn:
  // p = b*T+t (row), kd = h*64+d (col)
  const int kd = h * DH_ + wid * 16 + l15;
  const int kpart = (kd >> 5) * 2 * 512 + ((kd >> 3) & 3) * 16 * 8 + (kd & 7);
#pragma unroll
  for (int r = 0; r < 4; r++) {
    const int q = quad * 4 + r;
    if (q < nqt) {
      const float inv = 0.5f / larr[q];
      const int t = ql[qlo + q];
      const int p = b * T_ + t;
      const long off = (long)(p >> 5) * 16384 + ((p >> 4) & 1) * 512
                       + (p & 15) * 8 + kpart;
      atomicAdd(attn + off, oacc[r] * inv);
    }
  }
}

// ---------------------------------------------------------------------------
extern "C" void kernel_launch(void* const* d_in, const int* in_sizes, int n_in,
                              void* d_out, int out_size, void* d_ws, size_t ws_size,
                              hipStream_t stream) {
  const float* query = (const float*)d_in[0];
  const float* key   = (const float*)d_in[1];
  const float* value = (const float*)d_in[2];
  const float* Wq = (const float*)d_in[3];
  const float* bq = (const float*)d_in[4];
  const float* Wk = (const float*)d_in[5];
  const float* bk = (const float*)d_in[6];
  const float* Wv = (const float*)d_in[7];
  const float* bv = (const float*)d_in[8];
  const float* Wo = (const float*)d_in[9];
  const float* bo = (const float*)d_in[10];
  const float* lshW = (const float*)d_in[11];
  const float* lshb = (const float*)d_in[12];

  const size_t MSZ = (size_t)M_ * E_;
  const size_t WSZ = (size_t)E_ * E_;
  float* Q    = (float*)d_ws;
  float* K    = Q + MSZ;
  float* V    = K + MSZ;
  float* attn = V + MSZ;
  int* qh     = (int*)(attn + MSZ);
  int* kh     = qh + NSEG * T_;
  int* klist  = kh + NSEG * T_;
  int* qlist  = klist + NSEG * T_;
  int* kcnt   = qlist + NSEG * T_;       // start of zeroed region
  int* qcnt   = kcnt + NSEG * NBUCKET;
  int* ntasks = qcnt + NSEG * NBUCKET;   // end of zeroed region
  int* kcur   = ntasks + 1;
  int* qcur   = kcur + NSEG * NBUCKET;
  int* koff   = qcur + NSEG * NBUCKET;
  int* qoff   = koff + NSEG * (NBUCKET + 1);
  int* tasks  = qoff + NSEG * (NBUCKET + 1);
  uint16_t* Woh = (uint16_t*)(((uintptr_t)(tasks + MAXTASK) + 15) & ~(uintptr_t)15);
  uint16_t* Wol = Woh + WSZ;
  uint16_t* Wqh = Wol + WSZ;
  uint16_t* Wql = Wqh + WSZ;
  uint16_t* Wkh = Wql + WSZ;
  uint16_t* Wkl = Wkh + WSZ;
  uint16_t* Wvh = Wkl + WSZ;
  uint16_t* Wvl = Wvh + WSZ;
  uint16_t* Xqh = Wvl + WSZ;
  uint16_t* Xql = Xqh + MSZ;
  uint16_t* Xkh = Xql + MSZ;
  uint16_t* Xkl = Xkh + MSZ;
  uint16_t* Xvh = Xkl + MSZ;
  uint16_t* Xvl = Xvh + MSZ;
  uint16_t* Lwh = Xvl + MSZ;
  uint16_t* Lwl = Lwh + (size_t)NROUND * DH_ * DH_;

  prep_kernel<<<dim3(1921), 256, 0, stream>>>(
      query, key, value, Wq, Wk, Wv, Wo, lshW,
      Xqh, Xql, Xkh, Xkl, Xvh, Xvl,
      Wqh, Wql, Wkh, Wkl, Wvh, Wvl, Woh, Wol,
      Lwh, Lwl, attn, kcnt);
  proj_mfma<<<dim3(M_ / 128, E_ / 64, 3), 256, 0, stream>>>(
      Xqh, Xql, Xkh, Xkl, Xvh, Xvl,
      Wqh, Wql, Wkh, Wkl, Wvh, Wvl,
      bq, bk, bv, Q, K, V);
  hash_mfma<<<dim3(M_ * H_ / 128, 4), 256, 0, stream>>>(
      Q, K, Lwh, Lwl, lshb, qh, kh, qcnt, kcnt);
  scan_kernel<<<dim3(2), 1024, 0, stream>>>(kcnt, koff, kcur, qcnt, qoff, qcur,
                                            ntasks, tasks);
  scatter2_kernel<<<dim3(NSEG * T_ / 256, 2), 256, 0, stream>>>(
      kh, qh, kcur, qcur, klist, qlist);
  attn_task<<<dim3(MAXTASK), 256, 0, stream>>>(
      Q, K, V, qlist, qoff, klist, koff, tasks, ntasks, attn);
  mfma_gemm<<<dim3(M_ / 128, E_ / 64), 256, 0, stream>>>(
      attn, Woh, Wol, bo, (float*)d_out);
}

// Round 14
// 193.448 us; speedup vs baseline: 1.1223x; 1.0845x over previous
//
#include <hip/hip_runtime.h>
#include <stdint.h>
#include <math.h>

// ReformerAttention on MI355X — fp32 I/O. B=2,T=2048,E=512,H=8,Dh=64,
// 2 hash rounds, buckets<32 attend.
// Projection row p = logical (b'=p>>11, t'=p&2047); gathers input row (b=p&1, t=p>>1).
//
// 7 launches:
//   prep (fp16 2-way split of q/k/v/Wq/Wk/Wv + bf16 hi/lo Wo, TILED dest-linear;
//         + lshW split + zero attn/ntasks)
//   -> proj_mfma (fused Q,K,V projections, fp16 3-term, tiled operands)
//   -> hash_mfma (LDS-staged A, NO atomics — writes outh only)
//   -> hist_scatter (per-seg block: LDS histogram + LDS-cursor scatter;
//                    ZERO global atomics; writes cnt + klist/qlist)
//   -> scan (off + tasks) -> attn_task (MFMA, 16-q, K-pipelined)
//   -> mfma_gemm(out, tiled-A + tiled-B, perm)
//
// r13 discovery: hash_mfma was 46.6us at MfmaUtil 2.4 / VALU 11 / HBM 3 /
//   occ 19 — GPU 89% idle. Cause: ~65k device-scope atomicAdds on an 8KB
//   (128-line) counter region from all XCDs at once -> home-L2 same-line
//   serialization ~100k cy. (Old fp32 hash, same atomics: 54us — the ~40us
//   floor was the atomics all along.) scatter2 had the identical pattern
//   (131k return-value atomics, same region) — also suspect.
//   r14: remove ALL global histogram/cursor atomics. hash writes outh only;
//   hist_scatter owns one seg per block (exclusive) -> LDS hist + plain cnt
//   stores + LDS-cursor position assignment. Within-bucket order arbitrary
//   (was arbitrary before — atomic arrival order).
// Tiled layouts (elem offsets, fp16/bf16/fp32 units):
//   A[mb][ks][half]: ((mb*32 + ks*2 + half)*64 + lane)*8,
//     row=mb*32+half*16+(lane&15), k=ks*32+(lane>>4)*8
//   B[nb][ks]: ((nb*16 + ks)*64 + lane)*8, col=nb*16+(lane&15), k=ks*32+(lane>>4)*8
// Q,K precision: x = h + l/4096 fp16 split (verified r2-r13, argmax-safe).
// attn v12 (r13): MFMA wave-split, 16-q tasks, K-gather reg-pipelined.

#define T_ 2048
#define E_ 512
#define H_ 8
#define DH_ 64
#define B_ 2
#define M_ 4096
#define NROUND 2
#define NBUCKET 32
#define NSEG 32
#define MAXTASK 5120

typedef short v8s __attribute__((ext_vector_type(8)));
typedef _Float16 v8h __attribute__((ext_vector_type(8)));
typedef float v4f __attribute__((ext_vector_type(4)));

__device__ __forceinline__ float bf2f(uint16_t u) {
  union { uint32_t i; float f; } v; v.i = ((uint32_t)u) << 16; return v.f;
}
__device__ __forceinline__ uint16_t f2bf(float f) {
  union { float fv; uint32_t i; } v; v.fv = f;
  uint32_t x = v.i;
  x += 0x7fffu + ((x >> 16) & 1u);   // RN-even
  return (uint16_t)(x >> 16);
}
__device__ __forceinline__ void split8(const float4 a, const float4 b,
                                       v8s& h, v8s& l) {
  const float x[8] = {a.x, a.y, a.z, a.w, b.x, b.y, b.z, b.w};
#pragma unroll
  for (int j = 0; j < 8; j++) {
    const uint16_t hh = f2bf(x[j]);
    h[j] = (short)hh;
    l[j] = (short)f2bf(x[j] - bf2f(hh));
  }
}
// 2-way fp16 split with scaled residual: x = h + l*2^-12, no fp16 subnormals.
__device__ __forceinline__ void split2h8(const float4 a, const float4 b,
                                         v8h& h, v8h& l) {
  const float x[8] = {a.x, a.y, a.z, a.w, b.x, b.y, b.z, b.w};
#pragma unroll
  for (int j = 0; j < 8; j++) {
    const float xv = x[j];
    const _Float16 hh = (fabsf(xv) < 6.1035156e-5f) ? (_Float16)0.0f
                                                    : (_Float16)xv;
    const float r = xv - (float)hh;          // exact (Sterbenz / hh==0)
    h[j] = hh;
    l[j] = (_Float16)(r * 4096.0f);
  }
}

// ---------------------------------------------------------------------------
// prep v9: staging into tiled fragment layouts, DEST-LINEAR.
//   blocks [0,384)     : q/k/v fp16 split, gathered, tiled (block per mb)
//   blocks [384,896)   : Wq/Wk/Wv fp16 + Wo bf16 splits, tiled
//   blocks [896,1920)  : zero attn
//   block  1920        : zero ntasks region + lshW fp16 split
// ---------------------------------------------------------------------------
__global__ __launch_bounds__(256) void prep_kernel(
    const float* __restrict__ Xq, const float* __restrict__ Xk,
    const float* __restrict__ Xv,
    const float* __restrict__ Wq, const float* __restrict__ Wk,
    const float* __restrict__ Wv, const float* __restrict__ Wo,
    const float* __restrict__ lshW,
    uint16_t* __restrict__ Xqh, uint16_t* __restrict__ Xql,
    uint16_t* __restrict__ Xkh, uint16_t* __restrict__ Xkl,
    uint16_t* __restrict__ Xvh, uint16_t* __restrict__ Xvl,
    uint16_t* __restrict__ Wqh, uint16_t* __restrict__ Wql,
    uint16_t* __restrict__ Wkh, uint16_t* __restrict__ Wkl,
    uint16_t* __restrict__ Wvh, uint16_t* __restrict__ Wvl,
    uint16_t* __restrict__ Woh, uint16_t* __restrict__ Wol,
    uint16_t* __restrict__ Lwh, uint16_t* __restrict__ Lwl,
    float* __restrict__ attn, int* __restrict__ cnt)
{
  const int bid = blockIdx.x;
  const int tid = threadIdx.x;

  if (bid < 384) {                       // q/k/v fp16 split (gathered, tiled)
    const int sel = bid >> 7;            // 0=q,1=k,2=v
    const int mb  = bid & 127;           // 32-row block
    const float* X = (sel == 0) ? Xq : (sel == 1) ? Xk : Xv;
    uint16_t* H = (sel == 0) ? Xqh : (sel == 1) ? Xkh : Xvh;
    uint16_t* L = (sel == 0) ? Xql : (sel == 1) ? Xkl : Xvl;
#pragma unroll
    for (int it = 0; it < 8; it++) {
      const int g = it * 256 + tid;      // chunk within mb: [0,2048)
      const int f = g >> 6;              // frag 0..31 (ks*2+half)
      const int lane = g & 63;
      const int ks = f >> 1, half = f & 1;
      const int p = mb * 32 + half * 16 + (lane & 15);
      const int k = ks * 32 + (lane >> 4) * 8;
      const long src = ((long)(p & 1) * T_ + (p >> 1)) * E_ + k;
      const float4 a = *(const float4*)(X + src);
      const float4 b = *(const float4*)(X + src + 4);
      v8h h, l;
      split2h8(a, b, h, l);
      const long dst = (long)mb * 16384 + (long)g * 8;
      *(v8h*)(H + dst) = h;
      *(v8h*)(L + dst) = l;
    }
    return;
  }

  if (bid < 896) {                       // weight splits, tiled, dest-linear
    const int wsel = (bid - 384) >> 7;   // 0=Wq,1=Wk,2=Wv,3=Wo
    const int g2 = ((bid - 384) & 127) * 256 + tid;   // chunk [0,32768)
    const int f = g2 >> 6;               // frag 0..511 (nb*16+ks)
    const int lane = g2 & 63;
    const int nb = f >> 4, ks = f & 15;
    const int n = nb * 16 + (lane & 15);
    const int k = ks * 32 + (lane >> 4) * 8;
    const long src = (long)n * E_ + k;
    const long dst = (long)g2 * 8;
    if (wsel < 3) {
      const float* S = (wsel == 0) ? Wq : (wsel == 1) ? Wk : Wv;
      const float4 a = *(const float4*)(S + src);
      const float4 b = *(const float4*)(S + src + 4);
      v8h h, l;
      split2h8(a, b, h, l);
      uint16_t* H = (wsel == 0) ? Wqh : (wsel == 1) ? Wkh : Wvh;
      uint16_t* L = (wsel == 0) ? Wql : (wsel == 1) ? Wkl : Wvl;
      *(v8h*)(H + dst) = h;
      *(v8h*)(L + dst) = l;
    } else {
      const float4 a = *(const float4*)(Wo + src);
      const float4 b = *(const float4*)(Wo + src + 4);
      v8s h, l;
      split8(a, b, h, l);
      *(v8s*)(Woh + dst) = h;
      *(v8s*)(Wol + dst) = l;
    }
    return;
  }

  if (bid < 1920) {                      // zero attn: 1024 blocks x 512 float4
    float4* a4 = (float4*)attn;
    const int g = (bid - 896) * 512 + tid * 2;
    a4[g] = make_float4(0.f, 0.f, 0.f, 0.f);
    a4[g + 1] = make_float4(0.f, 0.f, 0.f, 0.f);
    return;
  }

  for (int i = tid; i < 2 * NSEG * NBUCKET + 1; i += 256) cnt[i] = 0;
  for (int i = tid; i < NROUND * DH_ * DH_; i += 256) {  // lshW fp16 split
    const float xv = lshW[i];
    const _Float16 hh = (fabsf(xv) < 6.1035156e-5f) ? (_Float16)0.0f
                                                    : (_Float16)xv;
    const float r = xv - (float)hh;
    *(_Float16*)(Lwh + i) = hh;
    *(_Float16*)(Lwl + i) = (_Float16)(r * 4096.0f);
  }
}

// ---------------------------------------------------------------------------
// proj_mfma v6: fused Q/K/V projections, fp16 3-term, TILED operands.
// grid (32, 8, 3) = 768 blocks; 2x4 16x16 tiles/wave (32x64).
// ---------------------------------------------------------------------------
__global__ __launch_bounds__(256) void proj_mfma(
    const uint16_t* __restrict__ Aqh, const uint16_t* __restrict__ Aql,
    const uint16_t* __restrict__ Akh, const uint16_t* __restrict__ Akl,
    const uint16_t* __restrict__ Avh, const uint16_t* __restrict__ Avl,
    const uint16_t* __restrict__ Bqh, const uint16_t* __restrict__ Bql,
    const uint16_t* __restrict__ Bkh, const uint16_t* __restrict__ Bkl,
    const uint16_t* __restrict__ Bvh, const uint16_t* __restrict__ Bvl,
    const float* __restrict__ bq, const float* __restrict__ bk,
    const float* __restrict__ bv,
    float* __restrict__ Qo, float* __restrict__ Ko, float* __restrict__ Vo)
{
  const uint16_t *Ah, *Al, *Bh, *Bl;
  const float* bias; float* C;
  if (blockIdx.z == 0)      { Ah = Aqh; Al = Aql; Bh = Bqh; Bl = Bql; bias = bq; C = Qo; }
  else if (blockIdx.z == 1) { Ah = Akh; Al = Akl; Bh = Bkh; Bl = Bkl; bias = bk; C = Ko; }
  else                      { Ah = Avh; Al = Avl; Bh = Bvh; Bl = Bvl; bias = bv; C = Vo; }

  const int wid = threadIdx.x >> 6, lane = threadIdx.x & 63;
  const int mb = blockIdx.x * 4 + wid;        // 32-row block
  const int nb0 = blockIdx.y * 4;             // first 16-col block
  const int m0 = mb * 32, n0 = blockIdx.y * 64;
  const int l15 = lane & 15, quad = lane >> 4;

  const long aB = (long)mb * 16384 + lane * 8;
  long bB[4];
#pragma unroll
  for (int j = 0; j < 4; j++) bB[j] = (long)(nb0 + j) * 8192 + lane * 8;

  v4f accH[2][4] = {};
  v4f accX[2][4] = {};

  v8h ah0 = *(const v8h*)(Ah + aB);
  v8h ah1 = *(const v8h*)(Ah + aB + 512);
  v8h al0 = *(const v8h*)(Al + aB);
  v8h al1 = *(const v8h*)(Al + aB + 512);
  v8h bh[4], bl[4];
#pragma unroll
  for (int j = 0; j < 4; j++) {
    bh[j] = *(const v8h*)(Bh + bB[j]);
    bl[j] = *(const v8h*)(Bl + bB[j]);
  }

  for (int ks = 0; ks < 16; ks++) {
    const int kn = (ks + 1) & 15;   // wraps on last iter; values unused
    const v8h nah0 = *(const v8h*)(Ah + aB + kn * 1024);
    const v8h nah1 = *(const v8h*)(Ah + aB + kn * 1024 + 512);
    const v8h nal0 = *(const v8h*)(Al + aB + kn * 1024);
    const v8h nal1 = *(const v8h*)(Al + aB + kn * 1024 + 512);
    v8h nbh[4], nbl[4];
#pragma unroll
    for (int j = 0; j < 4; j++) {
      nbh[j] = *(const v8h*)(Bh + bB[j] + kn * 512);
      nbl[j] = *(const v8h*)(Bl + bB[j] + kn * 512);
    }

#pragma unroll
    for (int j = 0; j < 4; j++) {
      accH[0][j] = __builtin_amdgcn_mfma_f32_16x16x32_f16(ah0, bh[j], accH[0][j], 0, 0, 0);
      accH[1][j] = __builtin_amdgcn_mfma_f32_16x16x32_f16(ah1, bh[j], accH[1][j], 0, 0, 0);
    }
#pragma unroll
    for (int j = 0; j < 4; j++) {
      accX[0][j] = __builtin_amdgcn_mfma_f32_16x16x32_f16(ah0, bl[j], accX[0][j], 0, 0, 0);
      accX[1][j] = __builtin_amdgcn_mfma_f32_16x16x32_f16(ah1, bl[j], accX[1][j], 0, 0, 0);
    }
#pragma unroll
    for (int j = 0; j < 4; j++) {
      accX[0][j] = __builtin_amdgcn_mfma_f32_16x16x32_f16(al0, bh[j], accX[0][j], 0, 0, 0);
      accX[1][j] = __builtin_amdgcn_mfma_f32_16x16x32_f16(al1, bh[j], accX[1][j], 0, 0, 0);
    }

    ah0 = nah0; al0 = nal0; ah1 = nah1; al1 = nal1;
#pragma unroll
    for (int j = 0; j < 4; j++) { bh[j] = nbh[j]; bl[j] = nbl[j]; }
  }

#pragma unroll
  for (int i = 0; i < 2; i++)
#pragma unroll
    for (int j = 0; j < 4; j++) {
      const int colg = n0 + j * 16 + l15;
      const float bb = bias[colg];
#pragma unroll
      for (int r = 0; r < 4; r++) {
        const int mm = m0 + i * 16 + quad * 4 + r;
        C[(long)mm * E_ + colg] =
            accH[i][j][r] + accX[i][j][r] * (1.0f / 4096.0f) + bb;
      }
    }
}

// ---------------------------------------------------------------------------
// mfma_gemm v8 (out-projection): bf16 3-term, tiled A+B, permC write.
// ---------------------------------------------------------------------------
__global__ __launch_bounds__(256) void mfma_gemm(
    const float* __restrict__ A,
    const uint16_t* __restrict__ Bht, const uint16_t* __restrict__ Blt,
    const float* __restrict__ bias, float* __restrict__ C)
{
  const int wid = threadIdx.x >> 6, lane = threadIdx.x & 63;
  const int mb = blockIdx.x * 4 + wid;
  const int m0 = mb * 32;
  const int nb0 = blockIdx.y * 4;
  const int n0 = blockIdx.y * 64;
  const int l15 = lane & 15, quad = lane >> 4;

  const long aB = (long)mb * 16384 + lane * 8;   // fp32 elems, tiled
  long bB[4];
#pragma unroll
  for (int j = 0; j < 4; j++) bB[j] = (long)(nb0 + j) * 8192 + lane * 8;

  v4f acc[2][4] = {};
  for (int ks = 0; ks < 16; ks++) {
    const long a0 = aB + ks * 1024;     // half 0
    const long a1 = a0 + 512;           // half 1
    v8s ah0, al0, ah1, al1;
    split8(*(const float4*)(A + a0), *(const float4*)(A + a0 + 4), ah0, al0);
    split8(*(const float4*)(A + a1), *(const float4*)(A + a1 + 4), ah1, al1);
    v8s bh[4], bl[4];
#pragma unroll
    for (int j = 0; j < 4; j++) {
      bh[j] = *(const v8s*)(Bht + bB[j] + ks * 512);
      bl[j] = *(const v8s*)(Blt + bB[j] + ks * 512);
    }
#pragma unroll
    for (int j = 0; j < 4; j++) {
      acc[0][j] = __builtin_amdgcn_mfma_f32_16x16x32_bf16(ah0, bh[j], acc[0][j], 0, 0, 0);
      acc[1][j] = __builtin_amdgcn_mfma_f32_16x16x32_bf16(ah1, bh[j], acc[1][j], 0, 0, 0);
    }
#pragma unroll
    for (int j = 0; j < 4; j++) {
      acc[0][j] = __builtin_amdgcn_mfma_f32_16x16x32_bf16(ah0, bl[j], acc[0][j], 0, 0, 0);
      acc[1][j] = __builtin_amdgcn_mfma_f32_16x16x32_bf16(ah1, bl[j], acc[1][j], 0, 0, 0);
    }
#pragma unroll
    for (int j = 0; j < 4; j++) {
      acc[0][j] = __builtin_amdgcn_mfma_f32_16x16x32_bf16(al0, bh[j], acc[0][j], 0, 0, 0);
      acc[1][j] = __builtin_amdgcn_mfma_f32_16x16x32_bf16(al1, bh[j], acc[1][j], 0, 0, 0);
    }
  }

#pragma unroll
  for (int i = 0; i < 2; i++)
#pragma unroll
    for (int j = 0; j < 4; j++) {
      const int colg = n0 + j * 16 + l15;
      const float bb = bias[colg];
#pragma unroll
      for (int r = 0; r < 4; r++) {
        const int mm = m0 + i * 16 + quad * 4 + r;
        const int crow = (mm & (T_ - 1)) * B_ + (mm >> 11);
        C[(long)crow * E_ + colg] = acc[i][j][r] + bb;
      }
    }
}

// ---------------------------------------------------------------------------
// hash_mfma v6: LSH hash, LDS-staged A, 3-term fp16 MFMA, in-reg argmax.
// NO global atomics — writes outh only (histogram moved to hist_scatter).
// grid (256, 4): y = src*2 + r; 256 thr; wave does 32 rows.
// ---------------------------------------------------------------------------
__global__ __launch_bounds__(256) void hash_mfma(
    const float* __restrict__ Q, const float* __restrict__ K,
    const uint16_t* __restrict__ Lwh, const uint16_t* __restrict__ Lwl,
    const float* __restrict__ lshb,
    int* __restrict__ qh, int* __restrict__ kh)
{
  __shared__ __align__(16) float xs[128][68];

  const int comb = blockIdx.y;               // 0..3
  const int src = comb >> 1, r = comb & 1;
  const float* X = src ? K : Q;
  int* outh = src ? kh : qh;

  const int tid = threadIdx.x;
  const int wid = tid >> 6, lane = tid & 63;
  const int blockBase = blockIdx.x * 128;    // head-row base for block
  const int m0 = blockBase + wid * 32;       // head-row base for wave
  const int l15 = lane & 15, quad = lane >> 4;

  // coalesced stage: 128 rows x 64 floats = 2048 float4, 256 thr x 8 iters
  const float4* src4 = (const float4*)(X + (long)blockBase * DH_);
#pragma unroll
  for (int it = 0; it < 8; it++) {
    const int g = it * 256 + tid;
    const int row = g >> 4, c4 = g & 15;
    *(float4*)&xs[row][c4 * 4] = src4[g];
  }

  v8h bh[4][2], bl[4][2];
#pragma unroll
  for (int n = 0; n < 4; n++)
#pragma unroll
    for (int k = 0; k < 2; k++) {
      const int o = r * (DH_ * DH_) + (n * 16 + l15) * DH_ + k * 32 + quad * 8;
      bh[n][k] = *(const v8h*)(Lwh + o);
      bl[n][k] = *(const v8h*)(Lwl + o);
    }
  __syncthreads();

  v4f accH[2][4] = {};
  v4f accX[2][4] = {};
#pragma unroll
  for (int k = 0; k < 2; k++) {
#pragma unroll
    for (int i = 0; i < 2; i++) {
      const int lrow = wid * 32 + i * 16 + l15;
      const float4 a = *(const float4*)&xs[lrow][k * 32 + quad * 8];
      const float4 c = *(const float4*)&xs[lrow][k * 32 + quad * 8 + 4];
      v8h ah, al;
      split2h8(a, c, ah, al);
#pragma unroll
      for (int n = 0; n < 4; n++) {
        accH[i][n] = __builtin_amdgcn_mfma_f32_16x16x32_f16(ah, bh[n][k], accH[i][n], 0, 0, 0);
        accX[i][n] = __builtin_amdgcn_mfma_f32_16x16x32_f16(ah, bl[n][k], accX[i][n], 0, 0, 0);
        accX[i][n] = __builtin_amdgcn_mfma_f32_16x16x32_f16(al, bh[n][k], accX[i][n], 0, 0, 0);
      }
    }
  }

  float bb[4];
#pragma unroll
  for (int n = 0; n < 4; n++) bb[n] = lshb[r * DH_ + n * 16 + l15];

#pragma unroll
  for (int i = 0; i < 2; i++)
#pragma unroll
    for (int reg = 0; reg < 4; reg++) {
      float bv = -INFINITY; int bi = 0x7fffffff;
#pragma unroll
      for (int n = 0; n < 4; n++) {
        const float v = accH[i][n][reg] + accX[i][n][reg] * (1.0f / 4096.0f)
                        + bb[n];
        const int idx = n * 16 + l15;
        if (v > bv || (v == bv && idx < bi)) { bv = v; bi = idx; }
      }
#pragma unroll
      for (int d = 8; d >= 1; d >>= 1) {
        const float ov = __shfl_xor(bv, d);
        const int oi = __shfl_xor(bi, d);
        if (ov > bv || (ov == bv && oi < bi)) { bv = ov; bi = oi; }
      }
      if (l15 == 0) {
        const int hr = m0 + i * 16 + quad * 4 + reg;
        const int p = hr >> 3, hh = hr & 7;
        const int bt = p >> 11, t = p & (T_ - 1);
        const int seg = r * 16 + bt * H_ + hh;
        outh[seg * T_ + t] = bi;
      }
    }
}

// ---------------------------------------------------------------------------
// hist_scatter (r14, replaces scatter2 + hash histogram): grid (32, 2);
// block owns ONE (side, seg) exclusively. Reads the seg's 2048 hashes
// coalesced, LDS histogram (LDS atomics only), writes cnt with plain
// stores, 32-bucket shfl prefix, LDS-cursor position assignment, writes
// list[seg]. ZERO global atomics.
// ---------------------------------------------------------------------------
__global__ __launch_bounds__(256) void hist_scatter(
    const int* __restrict__ kh, const int* __restrict__ qh,
    int* __restrict__ kcnt, int* __restrict__ qcnt,
    int* __restrict__ klist, int* __restrict__ qlist)
{
  __shared__ int hist[NBUCKET];
  __shared__ int cursor[NBUCKET];

  const int seg = blockIdx.x;           // 0..31
  const int side = blockIdx.y;          // 0=k, 1=q
  const int* hsh = (side ? qh : kh) + (long)seg * T_;
  int* cnt = (side ? qcnt : kcnt) + seg * NBUCKET;
  int* list = (side ? qlist : klist) + (long)seg * T_;
  const int tid = threadIdx.x;

  if (tid < NBUCKET) hist[tid] = 0;
  __syncthreads();

  int v[8];
#pragma unroll
  for (int i = 0; i < 8; i++) {
    v[i] = hsh[i * 256 + tid];
    if (v[i] < NBUCKET) atomicAdd(&hist[v[i]], 1);
  }
  __syncthreads();

  // wave 0: write cnt + exclusive prefix into cursor
  if (tid < 64) {
    const int b = tid & 31;
    const int c = (tid < 32) ? hist[b] : 0;
    int s = c;
#pragma unroll
    for (int d = 1; d < 32; d <<= 1) {
      const int t = __shfl_up(s, d, 32);
      if (b >= d) s += t;
    }
    if (tid < 32) {
      cnt[b] = c;
      cursor[b] = s - c;                // exclusive prefix
    }
  }
  __syncthreads();

#pragma unroll
  for (int i = 0; i < 8; i++) {
    if (v[i] < NBUCKET) {
      const int pos = atomicAdd(&cursor[v[i]], 1);
      list[pos] = i * 256 + tid;
    }
  }
}

// ---------------------------------------------------------------------------
// Scan v3: 2 blocks x 1024 threads; one thread per (seg,bucket).
// off prefix + 16-query task emission. (cur writes removed — unused now.)
// ---------------------------------------------------------------------------
__global__ __launch_bounds__(1024) void scan_kernel(
    const int* __restrict__ kcnt, int* __restrict__ koff,
    const int* __restrict__ qcnt, int* __restrict__ qoff,
    int* __restrict__ ntasks, int* __restrict__ tasks)
{
  const int tid = threadIdx.x;          // 0..1023
  const int isq = blockIdx.x;           // 0 = k-side, 1 = q-side
  const int seg = tid >> 5;             // 0..31
  const int b   = tid & 31;             // bucket
  const int* cnt = isq ? qcnt : kcnt;
  int* off = isq ? qoff : koff;

  const int c = cnt[seg * NBUCKET + b];

  int s = c;
#pragma unroll
  for (int d = 1; d < 32; d <<= 1) {
    const int t = __shfl_up(s, d, 32);
    if (b >= d) s += t;
  }
  const int excl = s - c;
  off[seg * (NBUCKET + 1) + b] = excl;
  if (b == 31) off[seg * (NBUCKET + 1) + NBUCKET] = s;

  if (isq) {
    const int nt = (c + 15) >> 4;       // 16-query tasks
    const int lane = tid & 63;
    int ws = nt;
#pragma unroll
    for (int d = 1; d < 64; d <<= 1) {
      const int t = __shfl_up(ws, d, 64);
      if (lane >= d) ws += t;
    }
    const int wtotal = __shfl(ws, 63, 64);
    int base = 0;
    if (lane == 63 && wtotal > 0) base = atomicAdd(ntasks, wtotal);
    base = __shfl(base, 63, 64);
    const int my = base + ws - nt;
    for (int i = 0; i < nt; i++)
      tasks[my + i] = (seg << 16) | (b << 8) | i;
  }
}

// ---------------------------------------------------------------------------
// attn_task v12: MFMA bucket attention, 16-query tasks, K-gather PIPELINED.
// Epilogue writes attn in TILED fp32 A-fragment layout.
// ---------------------------------------------------------------------------
__global__ __launch_bounds__(256) void attn_task(
    const float* __restrict__ Q, const float* __restrict__ K,
    const float* __restrict__ V,
    const int* __restrict__ qlist, const int* __restrict__ qoff,
    const int* __restrict__ klist, const int* __restrict__ koff,
    const int* __restrict__ tasks, const int* __restrict__ ntasks,
    float* __restrict__ attn)
{
  __shared__ __align__(16) float Plds[16][68];
  __shared__ __align__(16) float Vts[64][68];
  __shared__ float larr[16];

  if ((int)blockIdx.x >= *ntasks) return;
  const int tk = tasks[blockIdx.x];
  const int seg = tk >> 16, bucket = (tk >> 8) & 255, qt = tk & 255;
  const int ctx = seg & 15;
  const int b = ctx >> 3, h = ctx & 7;

  const int qlo = qoff[seg * (NBUCKET + 1) + bucket] + qt * 16;
  const int nqt = min(16, qoff[seg * (NBUCKET + 1) + bucket + 1] - qlo);
  const int klo = koff[seg * (NBUCKET + 1) + bucket];
  const int nk  = koff[seg * (NBUCKET + 1) + bucket + 1] - klo;
  if (nk == 0) return;

  const int tid = threadIdx.x;
  const int wid = tid >> 6, lane = tid & 63;
  const int l15 = lane & 15, quad = lane >> 4;
  const int r0 = tid >> 4, c4 = tid & 15;   // V-staging coords

  const float* Qb = Q + ((long)b * T_) * E_ + h * DH_;
  const float* Kb = K + ((long)b * T_) * E_ + h * DH_;
  const float* Vb = V + ((long)b * T_) * E_ + h * DH_;
  const int* ql = qlist + seg * T_;
  const int* kl = klist + seg * T_;

  if (tid < 16) larr[tid] = 0.f;

  // Q A-fragments: row=q=l15 (clamped), k=dim quad*8 (+32 per ks)
  const long qrow = (long)ql[qlo + min(l15, nqt - 1)] * E_;
  v8s qfh[2], qfl[2];
#pragma unroll
  for (int ks = 0; ks < 2; ks++) {
    const float4 a = *(const float4*)(Qb + qrow + ks * 32 + quad * 8);
    const float4 c = *(const float4*)(Qb + qrow + ks * 32 + quad * 8 + 4);
    split8(a, c, qfh[ks], qfl[ks]);
  }

  // K prologue: raw K float4s for tile 0 (this wave's 16 keys, cols=l15)
  float4 ka[2], kc[2];
  {
    const int key0 = wid * 16 + l15;
    const long kr0 = (long)kl[klo + min(key0, nk - 1)] * E_;
#pragma unroll
    for (int ks = 0; ks < 2; ks++) {
      ka[ks] = *(const float4*)(Kb + kr0 + ks * 32 + quad * 8);
      kc[ks] = *(const float4*)(Kb + kr0 + ks * 32 + quad * 8 + 4);
    }
  }
  __syncthreads();          // larr init visible before first atomics

  v4f oacc = {0.f, 0.f, 0.f, 0.f};

  for (int kt = 0; kt < nk; kt += 64) {
    // --- V tile loads into registers (latency hides under QK MFMAs) ---
    float4 vreg[4];
#pragma unroll
    for (int it = 0; it < 4; it++) {
      const int key = kt + it * 16 + r0;
      const long krow = (long)kl[klo + min(key, nk - 1)] * E_;
      vreg[it] = *(const float4*)(Vb + krow + c4 * 4);
    }

    // --- QK^T: consume pre-loaded K (bf16 3-term) ---
    const int keyg = kt + wid * 16 + l15;
    v4f sacc = {0.f, 0.f, 0.f, 0.f};
#pragma unroll
    for (int ks = 0; ks < 2; ks++) {
      v8s kfh, kfl;
      split8(ka[ks], kc[ks], kfh, kfl);
      sacc = __builtin_amdgcn_mfma_f32_16x16x32_bf16(qfh[ks], kfh, sacc, 0, 0, 0);
      sacc = __builtin_amdgcn_mfma_f32_16x16x32_bf16(qfh[ks], kfl, sacc, 0, 0, 0);
      sacc = __builtin_amdgcn_mfma_f32_16x16x32_bf16(qfl[ks], kfh, sacc, 0, 0, 0);
    }

    // --- prefetch next tile's K (in flight across softmax+stores+PV) ---
    {
      const int keyn = kt + 64 + wid * 16 + l15;
      const long krn = (long)kl[klo + min(keyn, nk - 1)] * E_;
#pragma unroll
      for (int ks = 0; ks < 2; ks++) {
        ka[ks] = *(const float4*)(Kb + krn + ks * 32 + quad * 8);
        kc[ks] = *(const float4*)(Kb + krn + ks * 32 + quad * 8 + 4);
      }
    }

    const bool kvalid = keyg < nk;
    const float p0 = kvalid ? __expf(sacc[0] * 0.125f) : 0.f;
    const float p1 = kvalid ? __expf(sacc[1] * 0.125f) : 0.f;
    const float p2 = kvalid ? __expf(sacc[2] * 0.125f) : 0.f;
    const float p3 = kvalid ? __expf(sacc[3] * 0.125f) : 0.f;

    float rs0 = p0, rs1 = p1, rs2 = p2, rs3 = p3;
#pragma unroll
    for (int d = 1; d < 16; d <<= 1) {
      rs0 += __shfl_xor(rs0, d);
      rs1 += __shfl_xor(rs1, d);
      rs2 += __shfl_xor(rs2, d);
      rs3 += __shfl_xor(rs3, d);
    }
    if (l15 == 0) {
      atomicAdd(&larr[quad * 4 + 0], rs0);
      atomicAdd(&larr[quad * 4 + 1], rs1);
      atomicAdd(&larr[quad * 4 + 2], rs2);
      atomicAdd(&larr[quad * 4 + 3], rs3);
    }
    Plds[quad * 4 + 0][wid * 16 + l15] = p0;
    Plds[quad * 4 + 1][wid * 16 + l15] = p1;
    Plds[quad * 4 + 2][wid * 16 + l15] = p2;
    Plds[quad * 4 + 3][wid * 16 + l15] = p3;

    // --- Vt transpose store (waits on vreg loads here, post-MFMA) ---
#pragma unroll
    for (int it = 0; it < 4; it++) {
      const int row = it * 16 + r0;
      Vts[c4 * 4 + 0][row] = vreg[it].x;
      Vts[c4 * 4 + 1][row] = vreg[it].y;
      Vts[c4 * 4 + 2][row] = vreg[it].z;
      Vts[c4 * 4 + 3][row] = vreg[it].w;
    }
    __syncthreads();

    // --- PV: this wave's 16 dims (cols = wid*16+l15), keys as K-dim ---
#pragma unroll
    for (int ks = 0; ks < 2; ks++) {
      const float4 pa = *(const float4*)&Plds[l15][ks * 32 + quad * 8];
      const float4 pb = *(const float4*)&Plds[l15][ks * 32 + quad * 8 + 4];
      v8s pah, pal;
      split8(pa, pb, pah, pal);
      const float4 va = *(const float4*)&Vts[wid * 16 + l15][ks * 32 + quad * 8];
      const float4 vb = *(const float4*)&Vts[wid * 16 + l15][ks * 32 + quad * 8 + 4];
      v8s vfh, vfl;
      split8(va, vb, vfh, vfl);
      oacc = __builtin_amdgcn_mfma_f32_16x16x32_bf16(pah, vfh, oacc, 0, 0, 0);
      oacc = __builtin_amdgcn_mfma_f32_16x16x32_bf16(pah, vfl, oacc, 0, 0, 0);
      oacc = __builtin_amdgcn_mfma_f32_16x16x32_bf16(pal, vfh, oacc, 0, 0, 0);
    }
    __syncthreads();
  }

  // epilogue: oacc row q=quad*4+r, col d=wid*16+l15; write TILED attn:
  // p = b*T+t (row), kd = h*64+d (col)
  const int kd = h * DH_ + wid * 16 + l15;
  const int kpart = (kd >> 5) * 2 * 512 + ((kd >> 3) & 3) * 16 * 8 + (kd & 7);
#pragma unroll
  for (int r = 0; r < 4; r++) {
    const int q = quad * 4 + r;
    if (q < nqt) {
      const float inv = 0.5f / larr[q];
      const int t = ql[qlo + q];
      const int p = b * T_ + t;
      const long off = (long)(p >> 5) * 16384 + ((p >> 4) & 1) * 512
                       + (p & 15) * 8 + kpart;
      atomicAdd(attn + off, oacc[r] * inv);
    }
  }
}

// ---------------------------------------------------------------------------
extern "C" void kernel_launch(void* const* d_in, const int* in_sizes, int n_in,
                              void* d_out, int out_size, void* d_ws, size_t ws_size,
                              hipStream_t stream) {
  const float* query = (const float*)d_in[0];
  const float* key   = (const float*)d_in[1];
  const float* value = (const float*)d_in[2];
  const float* Wq = (const float*)d_in[3];
  const float* bq = (const float*)d_in[4];
  const float* Wk = (const float*)d_in[5];
  const float* bk = (const float*)d_in[6];
  const float* Wv = (const float*)d_in[7];
  const float* bv = (const float*)d_in[8];
  const float* Wo = (const float*)d_in[9];
  const float* bo = (const float*)d_in[10];
  const float* lshW = (const float*)d_in[11];
  const float* lshb = (const float*)d_in[12];

  const size_t MSZ = (size_t)M_ * E_;
  const size_t WSZ = (size_t)E_ * E_;
  float* Q    = (float*)d_ws;
  float* K    = Q + MSZ;
  float* V    = K + MSZ;
  float* attn = V + MSZ;
  int* qh     = (int*)(attn + MSZ);
  int* kh     = qh + NSEG * T_;
  int* klist  = kh + NSEG * T_;
  int* qlist  = klist + NSEG * T_;
  int* kcnt   = qlist + NSEG * T_;       // start of zeroed region
  int* qcnt   = kcnt + NSEG * NBUCKET;
  int* ntasks = qcnt + NSEG * NBUCKET;   // end of zeroed region
  int* koff   = ntasks + 1;
  int* qoff   = koff + NSEG * (NBUCKET + 1);
  int* tasks  = qoff + NSEG * (NBUCKET + 1);
  uint16_t* Woh = (uint16_t*)(((uintptr_t)(tasks + MAXTASK) + 15) & ~(uintptr_t)15);
  uint16_t* Wol = Woh + WSZ;
  uint16_t* Wqh = Wol + WSZ;
  uint16_t* Wql = Wqh + WSZ;
  uint16_t* Wkh = Wql + WSZ;
  uint16_t* Wkl = Wkh + WSZ;
  uint16_t* Wvh = Wkl + WSZ;
  uint16_t* Wvl = Wvh + WSZ;
  uint16_t* Xqh = Wvl + WSZ;
  uint16_t* Xql = Xqh + MSZ;
  uint16_t* Xkh = Xql + MSZ;
  uint16_t* Xkl = Xkh + MSZ;
  uint16_t* Xvh = Xkl + MSZ;
  uint16_t* Xvl = Xvh + MSZ;
  uint16_t* Lwh = Xvl + MSZ;
  uint16_t* Lwl = Lwh + (size_t)NROUND * DH_ * DH_;

  prep_kernel<<<dim3(1921), 256, 0, stream>>>(
      query, key, value, Wq, Wk, Wv, Wo, lshW,
      Xqh, Xql, Xkh, Xkl, Xvh, Xvl,
      Wqh, Wql, Wkh, Wkl, Wvh, Wvl, Woh, Wol,
      Lwh, Lwl, attn, kcnt);
  proj_mfma<<<dim3(M_ / 128, E_ / 64, 3), 256, 0, stream>>>(
      Xqh, Xql, Xkh, Xkl, Xvh, Xvl,
      Wqh, Wql, Wkh, Wkl, Wvh, Wvl,
      bq, bk, bv, Q, K, V);
  hash_mfma<<<dim3(M_ * H_ / 128, 4), 256, 0, stream>>>(
      Q, K, Lwh, Lwl, lshb, qh, kh);
  hist_scatter<<<dim3(NSEG, 2), 256, 0, stream>>>(
      kh, qh, kcnt, qcnt, klist, qlist);
  scan_kernel<<<dim3(2), 1024, 0, stream>>>(kcnt, koff, qcnt, qoff,
                                            ntasks, tasks);
  attn_task<<<dim3(MAXTASK), 256, 0, stream>>>(
      Q, K, V, qlist, qoff, klist, koff, tasks, ntasks, attn);
  mfma_gemm<<<dim3(M_ / 128, E_ / 64), 256, 0, stream>>>(
      attn, Woh, Wol, bo, (float*)d_out);
}

// Round 15
// 192.601 us; speedup vs baseline: 1.1273x; 1.0044x over previous
//
#include <hip/hip_runtime.h>
#include <stdint.h>
#include <math.h>

// ReformerAttention on MI355X — fp32 I/O. B=2,T=2048,E=512,H=8,Dh=64,
// 2 hash rounds, buckets<32 attend.
// Projection row p = logical (b'=p>>11, t'=p&2047); gathers input row (b=p&1, t=p>>1).
//
// 6 launches:
//   prep (fp16 2-way split of q/k/v/Wq/Wk/Wv + bf16 hi/lo Wo, TILED dest-linear;
//         + lshW split + zero attn/ntasks)
//   -> proj_mfma (fused Q,K,V projections, fp16 3-term, tiled operands)
//   -> hash_mfma (LDS-staged A, NO atomics — writes outh only)
//   -> hist_scatter (per-seg block: LDS histogram, off prefix, list scatter,
//                    q-side task emission; only 32 single-counter atomics)
//   -> attn_task (MFMA, 16-q, K-pipelined) -> mfma_gemm(out, tiled, perm)
//
// r14 result: 193.4us (atomics theory CONFIRMED — removing ~200k clustered
//   device atomics on the 8KB counter region cut 16.4us; hash/scatter now
//   below the fill threshold). Top-5 = harness fills (2x ~44us, ~45% of
//   wall). r15: fold scan into hist_scatter (it already has the per-seg
//   histogram+prefix in LDS) — one fewer kernel + gap; cnt array dead.
// Tiled layouts (elem offsets, fp16/bf16/fp32 units):
//   A[mb][ks][half]: ((mb*32 + ks*2 + half)*64 + lane)*8,
//     row=mb*32+half*16+(lane&15), k=ks*32+(lane>>4)*8
//   B[nb][ks]: ((nb*16 + ks)*64 + lane)*8, col=nb*16+(lane&15), k=ks*32+(lane>>4)*8
// Q,K precision: x = h + l/4096 fp16 split (verified r2-r14, argmax-safe).
// attn v12 (r13): MFMA wave-split, 16-q tasks, K-gather reg-pipelined.

#define T_ 2048
#define E_ 512
#define H_ 8
#define DH_ 64
#define B_ 2
#define M_ 4096
#define NROUND 2
#define NBUCKET 32
#define NSEG 32
#define MAXTASK 5120

typedef short v8s __attribute__((ext_vector_type(8)));
typedef _Float16 v8h __attribute__((ext_vector_type(8)));
typedef float v4f __attribute__((ext_vector_type(4)));

__device__ __forceinline__ float bf2f(uint16_t u) {
  union { uint32_t i; float f; } v; v.i = ((uint32_t)u) << 16; return v.f;
}
__device__ __forceinline__ uint16_t f2bf(float f) {
  union { float fv; uint32_t i; } v; v.fv = f;
  uint32_t x = v.i;
  x += 0x7fffu + ((x >> 16) & 1u);   // RN-even
  return (uint16_t)(x >> 16);
}
__device__ __forceinline__ void split8(const float4 a, const float4 b,
                                       v8s& h, v8s& l) {
  const float x[8] = {a.x, a.y, a.z, a.w, b.x, b.y, b.z, b.w};
#pragma unroll
  for (int j = 0; j < 8; j++) {
    const uint16_t hh = f2bf(x[j]);
    h[j] = (short)hh;
    l[j] = (short)f2bf(x[j] - bf2f(hh));
  }
}
// 2-way fp16 split with scaled residual: x = h + l*2^-12, no fp16 subnormals.
__device__ __forceinline__ void split2h8(const float4 a, const float4 b,
                                         v8h& h, v8h& l) {
  const float x[8] = {a.x, a.y, a.z, a.w, b.x, b.y, b.z, b.w};
#pragma unroll
  for (int j = 0; j < 8; j++) {
    const float xv = x[j];
    const _Float16 hh = (fabsf(xv) < 6.1035156e-5f) ? (_Float16)0.0f
                                                    : (_Float16)xv;
    const float r = xv - (float)hh;          // exact (Sterbenz / hh==0)
    h[j] = hh;
    l[j] = (_Float16)(r * 4096.0f);
  }
}

// ---------------------------------------------------------------------------
// prep v9: staging into tiled fragment layouts, DEST-LINEAR.
//   blocks [0,384)     : q/k/v fp16 split, gathered, tiled (block per mb)
//   blocks [384,896)   : Wq/Wk/Wv fp16 + Wo bf16 splits, tiled
//   blocks [896,1920)  : zero attn
//   block  1920        : zero ntasks + lshW fp16 split
// ---------------------------------------------------------------------------
__global__ __launch_bounds__(256) void prep_kernel(
    const float* __restrict__ Xq, const float* __restrict__ Xk,
    const float* __restrict__ Xv,
    const float* __restrict__ Wq, const float* __restrict__ Wk,
    const float* __restrict__ Wv, const float* __restrict__ Wo,
    const float* __restrict__ lshW,
    uint16_t* __restrict__ Xqh, uint16_t* __restrict__ Xql,
    uint16_t* __restrict__ Xkh, uint16_t* __restrict__ Xkl,
    uint16_t* __restrict__ Xvh, uint16_t* __restrict__ Xvl,
    uint16_t* __restrict__ Wqh, uint16_t* __restrict__ Wql,
    uint16_t* __restrict__ Wkh, uint16_t* __restrict__ Wkl,
    uint16_t* __restrict__ Wvh, uint16_t* __restrict__ Wvl,
    uint16_t* __restrict__ Woh, uint16_t* __restrict__ Wol,
    uint16_t* __restrict__ Lwh, uint16_t* __restrict__ Lwl,
    float* __restrict__ attn, int* __restrict__ ntasks)
{
  const int bid = blockIdx.x;
  const int tid = threadIdx.x;

  if (bid < 384) {                       // q/k/v fp16 split (gathered, tiled)
    const int sel = bid >> 7;            // 0=q,1=k,2=v
    const int mb  = bid & 127;           // 32-row block
    const float* X = (sel == 0) ? Xq : (sel == 1) ? Xk : Xv;
    uint16_t* H = (sel == 0) ? Xqh : (sel == 1) ? Xkh : Xvh;
    uint16_t* L = (sel == 0) ? Xql : (sel == 1) ? Xkl : Xvl;
#pragma unroll
    for (int it = 0; it < 8; it++) {
      const int g = it * 256 + tid;      // chunk within mb: [0,2048)
      const int f = g >> 6;              // frag 0..31 (ks*2+half)
      const int lane = g & 63;
      const int ks = f >> 1, half = f & 1;
      const int p = mb * 32 + half * 16 + (lane & 15);
      const int k = ks * 32 + (lane >> 4) * 8;
      const long src = ((long)(p & 1) * T_ + (p >> 1)) * E_ + k;
      const float4 a = *(const float4*)(X + src);
      const float4 b = *(const float4*)(X + src + 4);
      v8h h, l;
      split2h8(a, b, h, l);
      const long dst = (long)mb * 16384 + (long)g * 8;
      *(v8h*)(H + dst) = h;
      *(v8h*)(L + dst) = l;
    }
    return;
  }

  if (bid < 896) {                       // weight splits, tiled, dest-linear
    const int wsel = (bid - 384) >> 7;   // 0=Wq,1=Wk,2=Wv,3=Wo
    const int g2 = ((bid - 384) & 127) * 256 + tid;   // chunk [0,32768)
    const int f = g2 >> 6;               // frag 0..511 (nb*16+ks)
    const int lane = g2 & 63;
    const int nb = f >> 4, ks = f & 15;
    const int n = nb * 16 + (lane & 15);
    const int k = ks * 32 + (lane >> 4) * 8;
    const long src = (long)n * E_ + k;
    const long dst = (long)g2 * 8;
    if (wsel < 3) {
      const float* S = (wsel == 0) ? Wq : (wsel == 1) ? Wk : Wv;
      const float4 a = *(const float4*)(S + src);
      const float4 b = *(const float4*)(S + src + 4);
      v8h h, l;
      split2h8(a, b, h, l);
      uint16_t* H = (wsel == 0) ? Wqh : (wsel == 1) ? Wkh : Wvh;
      uint16_t* L = (wsel == 0) ? Wql : (wsel == 1) ? Wkl : Wvl;
      *(v8h*)(H + dst) = h;
      *(v8h*)(L + dst) = l;
    } else {
      const float4 a = *(const float4*)(Wo + src);
      const float4 b = *(const float4*)(Wo + src + 4);
      v8s h, l;
      split8(a, b, h, l);
      *(v8s*)(Woh + dst) = h;
      *(v8s*)(Wol + dst) = l;
    }
    return;
  }

  if (bid < 1920) {                      // zero attn: 1024 blocks x 512 float4
    float4* a4 = (float4*)attn;
    const int g = (bid - 896) * 512 + tid * 2;
    a4[g] = make_float4(0.f, 0.f, 0.f, 0.f);
    a4[g + 1] = make_float4(0.f, 0.f, 0.f, 0.f);
    return;
  }

  if (tid == 0) *ntasks = 0;
  for (int i = tid; i < NROUND * DH_ * DH_; i += 256) {  // lshW fp16 split
    const float xv = lshW[i];
    const _Float16 hh = (fabsf(xv) < 6.1035156e-5f) ? (_Float16)0.0f
                                                    : (_Float16)xv;
    const float r = xv - (float)hh;
    *(_Float16*)(Lwh + i) = hh;
    *(_Float16*)(Lwl + i) = (_Float16)(r * 4096.0f);
  }
}

// ---------------------------------------------------------------------------
// proj_mfma v6: fused Q/K/V projections, fp16 3-term, TILED operands.
// grid (32, 8, 3) = 768 blocks; 2x4 16x16 tiles/wave (32x64).
// ---------------------------------------------------------------------------
__global__ __launch_bounds__(256) void proj_mfma(
    const uint16_t* __restrict__ Aqh, const uint16_t* __restrict__ Aql,
    const uint16_t* __restrict__ Akh, const uint16_t* __restrict__ Akl,
    const uint16_t* __restrict__ Avh, const uint16_t* __restrict__ Avl,
    const uint16_t* __restrict__ Bqh, const uint16_t* __restrict__ Bql,
    const uint16_t* __restrict__ Bkh, const uint16_t* __restrict__ Bkl,
    const uint16_t* __restrict__ Bvh, const uint16_t* __restrict__ Bvl,
    const float* __restrict__ bq, const float* __restrict__ bk,
    const float* __restrict__ bv,
    float* __restrict__ Qo, float* __restrict__ Ko, float* __restrict__ Vo)
{
  const uint16_t *Ah, *Al, *Bh, *Bl;
  const float* bias; float* C;
  if (blockIdx.z == 0)      { Ah = Aqh; Al = Aql; Bh = Bqh; Bl = Bql; bias = bq; C = Qo; }
  else if (blockIdx.z == 1) { Ah = Akh; Al = Akl; Bh = Bkh; Bl = Bkl; bias = bk; C = Ko; }
  else                      { Ah = Avh; Al = Avl; Bh = Bvh; Bl = Bvl; bias = bv; C = Vo; }

  const int wid = threadIdx.x >> 6, lane = threadIdx.x & 63;
  const int mb = blockIdx.x * 4 + wid;        // 32-row block
  const int nb0 = blockIdx.y * 4;             // first 16-col block
  const int m0 = mb * 32, n0 = blockIdx.y * 64;
  const int l15 = lane & 15, quad = lane >> 4;

  const long aB = (long)mb * 16384 + lane * 8;
  long bB[4];
#pragma unroll
  for (int j = 0; j < 4; j++) bB[j] = (long)(nb0 + j) * 8192 + lane * 8;

  v4f accH[2][4] = {};
  v4f accX[2][4] = {};

  v8h ah0 = *(const v8h*)(Ah + aB);
  v8h ah1 = *(const v8h*)(Ah + aB + 512);
  v8h al0 = *(const v8h*)(Al + aB);
  v8h al1 = *(const v8h*)(Al + aB + 512);
  v8h bh[4], bl[4];
#pragma unroll
  for (int j = 0; j < 4; j++) {
    bh[j] = *(const v8h*)(Bh + bB[j]);
    bl[j] = *(const v8h*)(Bl + bB[j]);
  }

  for (int ks = 0; ks < 16; ks++) {
    const int kn = (ks + 1) & 15;   // wraps on last iter; values unused
    const v8h nah0 = *(const v8h*)(Ah + aB + kn * 1024);
    const v8h nah1 = *(const v8h*)(Ah + aB + kn * 1024 + 512);
    const v8h nal0 = *(const v8h*)(Al + aB + kn * 1024);
    const v8h nal1 = *(const v8h*)(Al + aB + kn * 1024 + 512);
    v8h nbh[4], nbl[4];
#pragma unroll
    for (int j = 0; j < 4; j++) {
      nbh[j] = *(const v8h*)(Bh + bB[j] + kn * 512);
      nbl[j] = *(const v8h*)(Bl + bB[j] + kn * 512);
    }

#pragma unroll
    for (int j = 0; j < 4; j++) {
      accH[0][j] = __builtin_amdgcn_mfma_f32_16x16x32_f16(ah0, bh[j], accH[0][j], 0, 0, 0);
      accH[1][j] = __builtin_amdgcn_mfma_f32_16x16x32_f16(ah1, bh[j], accH[1][j], 0, 0, 0);
    }
#pragma unroll
    for (int j = 0; j < 4; j++) {
      accX[0][j] = __builtin_amdgcn_mfma_f32_16x16x32_f16(ah0, bl[j], accX[0][j], 0, 0, 0);
      accX[1][j] = __builtin_amdgcn_mfma_f32_16x16x32_f16(ah1, bl[j], accX[1][j], 0, 0, 0);
    }
#pragma unroll
    for (int j = 0; j < 4; j++) {
      accX[0][j] = __builtin_amdgcn_mfma_f32_16x16x32_f16(al0, bh[j], accX[0][j], 0, 0, 0);
      accX[1][j] = __builtin_amdgcn_mfma_f32_16x16x32_f16(al1, bh[j], accX[1][j], 0, 0, 0);
    }

    ah0 = nah0; al0 = nal0; ah1 = nah1; al1 = nal1;
#pragma unroll
    for (int j = 0; j < 4; j++) { bh[j] = nbh[j]; bl[j] = nbl[j]; }
  }

#pragma unroll
  for (int i = 0; i < 2; i++)
#pragma unroll
    for (int j = 0; j < 4; j++) {
      const int colg = n0 + j * 16 + l15;
      const float bb = bias[colg];
#pragma unroll
      for (int r = 0; r < 4; r++) {
        const int mm = m0 + i * 16 + quad * 4 + r;
        C[(long)mm * E_ + colg] =
            accH[i][j][r] + accX[i][j][r] * (1.0f / 4096.0f) + bb;
      }
    }
}

// ---------------------------------------------------------------------------
// mfma_gemm v8 (out-projection): bf16 3-term, tiled A+B, permC write.
// ---------------------------------------------------------------------------
__global__ __launch_bounds__(256) void mfma_gemm(
    const float* __restrict__ A,
    const uint16_t* __restrict__ Bht, const uint16_t* __restrict__ Blt,
    const float* __restrict__ bias, float* __restrict__ C)
{
  const int wid = threadIdx.x >> 6, lane = threadIdx.x & 63;
  const int mb = blockIdx.x * 4 + wid;
  const int m0 = mb * 32;
  const int nb0 = blockIdx.y * 4;
  const int n0 = blockIdx.y * 64;
  const int l15 = lane & 15, quad = lane >> 4;

  const long aB = (long)mb * 16384 + lane * 8;   // fp32 elems, tiled
  long bB[4];
#pragma unroll
  for (int j = 0; j < 4; j++) bB[j] = (long)(nb0 + j) * 8192 + lane * 8;

  v4f acc[2][4] = {};
  for (int ks = 0; ks < 16; ks++) {
    const long a0 = aB + ks * 1024;     // half 0
    const long a1 = a0 + 512;           // half 1
    v8s ah0, al0, ah1, al1;
    split8(*(const float4*)(A + a0), *(const float4*)(A + a0 + 4), ah0, al0);
    split8(*(const float4*)(A + a1), *(const float4*)(A + a1 + 4), ah1, al1);
    v8s bh[4], bl[4];
#pragma unroll
    for (int j = 0; j < 4; j++) {
      bh[j] = *(const v8s*)(Bht + bB[j] + ks * 512);
      bl[j] = *(const v8s*)(Blt + bB[j] + ks * 512);
    }
#pragma unroll
    for (int j = 0; j < 4; j++) {
      acc[0][j] = __builtin_amdgcn_mfma_f32_16x16x32_bf16(ah0, bh[j], acc[0][j], 0, 0, 0);
      acc[1][j] = __builtin_amdgcn_mfma_f32_16x16x32_bf16(ah1, bh[j], acc[1][j], 0, 0, 0);
    }
#pragma unroll
    for (int j = 0; j < 4; j++) {
      acc[0][j] = __builtin_amdgcn_mfma_f32_16x16x32_bf16(ah0, bl[j], acc[0][j], 0, 0, 0);
      acc[1][j] = __builtin_amdgcn_mfma_f32_16x16x32_bf16(ah1, bl[j], acc[1][j], 0, 0, 0);
    }
#pragma unroll
    for (int j = 0; j < 4; j++) {
      acc[0][j] = __builtin_amdgcn_mfma_f32_16x16x32_bf16(al0, bh[j], acc[0][j], 0, 0, 0);
      acc[1][j] = __builtin_amdgcn_mfma_f32_16x16x32_bf16(al1, bh[j], acc[1][j], 0, 0, 0);
    }
  }

#pragma unroll
  for (int i = 0; i < 2; i++)
#pragma unroll
    for (int j = 0; j < 4; j++) {
      const int colg = n0 + j * 16 + l15;
      const float bb = bias[colg];
#pragma unroll
      for (int r = 0; r < 4; r++) {
        const int mm = m0 + i * 16 + quad * 4 + r;
        const int crow = (mm & (T_ - 1)) * B_ + (mm >> 11);
        C[(long)crow * E_ + colg] = acc[i][j][r] + bb;
      }
    }
}

// ---------------------------------------------------------------------------
// hash_mfma v6: LSH hash, LDS-staged A, 3-term fp16 MFMA, in-reg argmax.
// NO global atomics — writes outh only.
// grid (256, 4): y = src*2 + r; 256 thr; wave does 32 rows.
// ---------------------------------------------------------------------------
__global__ __launch_bounds__(256) void hash_mfma(
    const float* __restrict__ Q, const float* __restrict__ K,
    const uint16_t* __restrict__ Lwh, const uint16_t* __restrict__ Lwl,
    const float* __restrict__ lshb,
    int* __restrict__ qh, int* __restrict__ kh)
{
  __shared__ __align__(16) float xs[128][68];

  const int comb = blockIdx.y;               // 0..3
  const int src = comb >> 1, r = comb & 1;
  const float* X = src ? K : Q;
  int* outh = src ? kh : qh;

  const int tid = threadIdx.x;
  const int wid = tid >> 6, lane = tid & 63;
  const int blockBase = blockIdx.x * 128;    // head-row base for block
  const int m0 = blockBase + wid * 32;       // head-row base for wave
  const int l15 = lane & 15, quad = lane >> 4;

  const float4* src4 = (const float4*)(X + (long)blockBase * DH_);
#pragma unroll
  for (int it = 0; it < 8; it++) {
    const int g = it * 256 + tid;
    const int row = g >> 4, c4 = g & 15;
    *(float4*)&xs[row][c4 * 4] = src4[g];
  }

  v8h bh[4][2], bl[4][2];
#pragma unroll
  for (int n = 0; n < 4; n++)
#pragma unroll
    for (int k = 0; k < 2; k++) {
      const int o = r * (DH_ * DH_) + (n * 16 + l15) * DH_ + k * 32 + quad * 8;
      bh[n][k] = *(const v8h*)(Lwh + o);
      bl[n][k] = *(const v8h*)(Lwl + o);
    }
  __syncthreads();

  v4f accH[2][4] = {};
  v4f accX[2][4] = {};
#pragma unroll
  for (int k = 0; k < 2; k++) {
#pragma unroll
    for (int i = 0; i < 2; i++) {
      const int lrow = wid * 32 + i * 16 + l15;
      const float4 a = *(const float4*)&xs[lrow][k * 32 + quad * 8];
      const float4 c = *(const float4*)&xs[lrow][k * 32 + quad * 8 + 4];
      v8h ah, al;
      split2h8(a, c, ah, al);
#pragma unroll
      for (int n = 0; n < 4; n++) {
        accH[i][n] = __builtin_amdgcn_mfma_f32_16x16x32_f16(ah, bh[n][k], accH[i][n], 0, 0, 0);
        accX[i][n] = __builtin_amdgcn_mfma_f32_16x16x32_f16(ah, bl[n][k], accX[i][n], 0, 0, 0);
        accX[i][n] = __builtin_amdgcn_mfma_f32_16x16x32_f16(al, bh[n][k], accX[i][n], 0, 0, 0);
      }
    }
  }

  float bb[4];
#pragma unroll
  for (int n = 0; n < 4; n++) bb[n] = lshb[r * DH_ + n * 16 + l15];

#pragma unroll
  for (int i = 0; i < 2; i++)
#pragma unroll
    for (int reg = 0; reg < 4; reg++) {
      float bv = -INFINITY; int bi = 0x7fffffff;
#pragma unroll
      for (int n = 0; n < 4; n++) {
        const float v = accH[i][n][reg] + accX[i][n][reg] * (1.0f / 4096.0f)
                        + bb[n];
        const int idx = n * 16 + l15;
        if (v > bv || (v == bv && idx < bi)) { bv = v; bi = idx; }
      }
#pragma unroll
      for (int d = 8; d >= 1; d >>= 1) {
        const float ov = __shfl_xor(bv, d);
        const int oi = __shfl_xor(bi, d);
        if (ov > bv || (ov == bv && oi < bi)) { bv = ov; bi = oi; }
      }
      if (l15 == 0) {
        const int hr = m0 + i * 16 + quad * 4 + reg;
        const int p = hr >> 3, hh = hr & 7;
        const int bt = p >> 11, t = p & (T_ - 1);
        const int seg = r * 16 + bt * H_ + hh;
        outh[seg * T_ + t] = bi;
      }
    }
}

// ---------------------------------------------------------------------------
// hist_scatter v2 (r15, absorbs scan): grid (32, 2); block owns ONE
// (side, seg). LDS histogram -> off[] prefix (plain stores), list scatter
// via LDS cursors; q-side additionally emits 16-query tasks (ONE
// atomicAdd(ntasks) per q-block = 32 total). No cnt array.
// ---------------------------------------------------------------------------
__global__ __launch_bounds__(256) void hist_scatter(
    const int* __restrict__ kh, const int* __restrict__ qh,
    int* __restrict__ koff, int* __restrict__ qoff,
    int* __restrict__ klist, int* __restrict__ qlist,
    int* __restrict__ ntasks, int* __restrict__ tasks)
{
  __shared__ int hist[NBUCKET];
  __shared__ int cursor[NBUCKET];

  const int seg = blockIdx.x;           // 0..31
  const int side = blockIdx.y;          // 0=k, 1=q
  const int* hsh = (side ? qh : kh) + (long)seg * T_;
  int* off = (side ? qoff : koff) + seg * (NBUCKET + 1);
  int* list = (side ? qlist : klist) + (long)seg * T_;
  const int tid = threadIdx.x;

  if (tid < NBUCKET) hist[tid] = 0;
  __syncthreads();

  int v[8];
#pragma unroll
  for (int i = 0; i < 8; i++) {
    v[i] = hsh[i * 256 + tid];
    if (v[i] < NBUCKET) atomicAdd(&hist[v[i]], 1);
  }
  __syncthreads();

  // wave 0, lanes 0..31: off prefix + cursor init (+ q-side task emission)
  if (tid < 64) {
    const int b = tid & 31;
    const int c = (tid < 32) ? hist[b] : 0;
    int s = c;
#pragma unroll
    for (int d = 1; d < 32; d <<= 1) {
      const int t = __shfl_up(s, d, 32);
      if (b >= d) s += t;
    }
    if (tid < 32) {
      off[b] = s - c;
      cursor[b] = s - c;                // exclusive prefix
      if (b == 31) off[NBUCKET] = s;
    }
    if (side == 1) {
      // task emission: nt 16-query tasks per bucket, prefix over buckets
      const int nt = (tid < 32) ? ((c + 15) >> 4) : 0;
      int ts = nt;
#pragma unroll
      for (int d = 1; d < 32; d <<= 1) {
        const int t = __shfl_up(ts, d, 32);
        if (b >= d) ts += t;
      }
      const int total = __shfl(ts, 31, 32);   // lanes 32..63 hold 0 -> use low half
      int base = 0;
      if (tid == 31 && total > 0) base = atomicAdd(ntasks, total);
      base = __shfl(base, 31, 32);
      if (tid < 32) {
        const int my = base + ts - nt;
        for (int i = 0; i < nt; i++)
          tasks[my + i] = (seg << 16) | (b << 8) | i;
      }
    }
  }
  __syncthreads();

#pragma unroll
  for (int i = 0; i < 8; i++) {
    if (v[i] < NBUCKET) {
      const int pos = atomicAdd(&cursor[v[i]], 1);
      list[pos] = i * 256 + tid;
    }
  }
}

// ---------------------------------------------------------------------------
// attn_task v12: MFMA bucket attention, 16-query tasks, K-gather PIPELINED.
// Epilogue writes attn in TILED fp32 A-fragment layout.
// ---------------------------------------------------------------------------
__global__ __launch_bounds__(256) void attn_task(
    const float* __restrict__ Q, const float* __restrict__ K,
    const float* __restrict__ V,
    const int* __restrict__ qlist, const int* __restrict__ qoff,
    const int* __restrict__ klist, const int* __restrict__ koff,
    const int* __restrict__ tasks, const int* __restrict__ ntasks,
    float* __restrict__ attn)
{
  __shared__ __align__(16) float Plds[16][68];
  __shared__ __align__(16) float Vts[64][68];
  __shared__ float larr[16];

  if ((int)blockIdx.x >= *ntasks) return;
  const int tk = tasks[blockIdx.x];
  const int seg = tk >> 16, bucket = (tk >> 8) & 255, qt = tk & 255;
  const int ctx = seg & 15;
  const int b = ctx >> 3, h = ctx & 7;

  const int qlo = qoff[seg * (NBUCKET + 1) + bucket] + qt * 16;
  const int nqt = min(16, qoff[seg * (NBUCKET + 1) + bucket + 1] - qlo);
  const int klo = koff[seg * (NBUCKET + 1) + bucket];
  const int nk  = koff[seg * (NBUCKET + 1) + bucket + 1] - klo;
  if (nk == 0) return;

  const int tid = threadIdx.x;
  const int wid = tid >> 6, lane = tid & 63;
  const int l15 = lane & 15, quad = lane >> 4;
  const int r0 = tid >> 4, c4 = tid & 15;   // V-staging coords

  const float* Qb = Q + ((long)b * T_) * E_ + h * DH_;
  const float* Kb = K + ((long)b * T_) * E_ + h * DH_;
  const float* Vb = V + ((long)b * T_) * E_ + h * DH_;
  const int* ql = qlist + seg * T_;
  const int* kl = klist + seg * T_;

  if (tid < 16) larr[tid] = 0.f;

  // Q A-fragments: row=q=l15 (clamped), k=dim quad*8 (+32 per ks)
  const long qrow = (long)ql[qlo + min(l15, nqt - 1)] * E_;
  v8s qfh[2], qfl[2];
#pragma unroll
  for (int ks = 0; ks < 2; ks++) {
    const float4 a = *(const float4*)(Qb + qrow + ks * 32 + quad * 8);
    const float4 c = *(const float4*)(Qb + qrow + ks * 32 + quad * 8 + 4);
    split8(a, c, qfh[ks], qfl[ks]);
  }

  // K prologue: raw K float4s for tile 0 (this wave's 16 keys, cols=l15)
  float4 ka[2], kc[2];
  {
    const int key0 = wid * 16 + l15;
    const long kr0 = (long)kl[klo + min(key0, nk - 1)] * E_;
#pragma unroll
    for (int ks = 0; ks < 2; ks++) {
      ka[ks] = *(const float4*)(Kb + kr0 + ks * 32 + quad * 8);
      kc[ks] = *(const float4*)(Kb + kr0 + ks * 32 + quad * 8 + 4);
    }
  }
  __syncthreads();          // larr init visible before first atomics

  v4f oacc = {0.f, 0.f, 0.f, 0.f};

  for (int kt = 0; kt < nk; kt += 64) {
    // --- V tile loads into registers (latency hides under QK MFMAs) ---
    float4 vreg[4];
#pragma unroll
    for (int it = 0; it < 4; it++) {
      const int key = kt + it * 16 + r0;
      const long krow = (long)kl[klo + min(key, nk - 1)] * E_;
      vreg[it] = *(const float4*)(Vb + krow + c4 * 4);
    }

    // --- QK^T: consume pre-loaded K (bf16 3-term) ---
    const int keyg = kt + wid * 16 + l15;
    v4f sacc = {0.f, 0.f, 0.f, 0.f};
#pragma unroll
    for (int ks = 0; ks < 2; ks++) {
      v8s kfh, kfl;
      split8(ka[ks], kc[ks], kfh, kfl);
      sacc = __builtin_amdgcn_mfma_f32_16x16x32_bf16(qfh[ks], kfh, sacc, 0, 0, 0);
      sacc = __builtin_amdgcn_mfma_f32_16x16x32_bf16(qfh[ks], kfl, sacc, 0, 0, 0);
      sacc = __builtin_amdgcn_mfma_f32_16x16x32_bf16(qfl[ks], kfh, sacc, 0, 0, 0);
    }

    // --- prefetch next tile's K (in flight across softmax+stores+PV) ---
    {
      const int keyn = kt + 64 + wid * 16 + l15;
      const long krn = (long)kl[klo + min(keyn, nk - 1)] * E_;
#pragma unroll
      for (int ks = 0; ks < 2; ks++) {
        ka[ks] = *(const float4*)(Kb + krn + ks * 32 + quad * 8);
        kc[ks] = *(const float4*)(Kb + krn + ks * 32 + quad * 8 + 4);
      }
    }

    const bool kvalid = keyg < nk;
    const float p0 = kvalid ? __expf(sacc[0] * 0.125f) : 0.f;
    const float p1 = kvalid ? __expf(sacc[1] * 0.125f) : 0.f;
    const float p2 = kvalid ? __expf(sacc[2] * 0.125f) : 0.f;
    const float p3 = kvalid ? __expf(sacc[3] * 0.125f) : 0.f;

    float rs0 = p0, rs1 = p1, rs2 = p2, rs3 = p3;
#pragma unroll
    for (int d = 1; d < 16; d <<= 1) {
      rs0 += __shfl_xor(rs0, d);
      rs1 += __shfl_xor(rs1, d);
      rs2 += __shfl_xor(rs2, d);
      rs3 += __shfl_xor(rs3, d);
    }
    if (l15 == 0) {
      atomicAdd(&larr[quad * 4 + 0], rs0);
      atomicAdd(&larr[quad * 4 + 1], rs1);
      atomicAdd(&larr[quad * 4 + 2], rs2);
      atomicAdd(&larr[quad * 4 + 3], rs3);
    }
    Plds[quad * 4 + 0][wid * 16 + l15] = p0;
    Plds[quad * 4 + 1][wid * 16 + l15] = p1;
    Plds[quad * 4 + 2][wid * 16 + l15] = p2;
    Plds[quad * 4 + 3][wid * 16 + l15] = p3;

    // --- Vt transpose store (waits on vreg loads here, post-MFMA) ---
#pragma unroll
    for (int it = 0; it < 4; it++) {
      const int row = it * 16 + r0;
      Vts[c4 * 4 + 0][row] = vreg[it].x;
      Vts[c4 * 4 + 1][row] = vreg[it].y;
      Vts[c4 * 4 + 2][row] = vreg[it].z;
      Vts[c4 * 4 + 3][row] = vreg[it].w;
    }
    __syncthreads();

    // --- PV: this wave's 16 dims (cols = wid*16+l15), keys as K-dim ---
#pragma unroll
    for (int ks = 0; ks < 2; ks++) {
      const float4 pa = *(const float4*)&Plds[l15][ks * 32 + quad * 8];
      const float4 pb = *(const float4*)&Plds[l15][ks * 32 + quad * 8 + 4];
      v8s pah, pal;
      split8(pa, pb, pah, pal);
      const float4 va = *(const float4*)&Vts[wid * 16 + l15][ks * 32 + quad * 8];
      const float4 vb = *(const float4*)&Vts[wid * 16 + l15][ks * 32 + quad * 8 + 4];
      v8s vfh, vfl;
      split8(va, vb, vfh, vfl);
      oacc = __builtin_amdgcn_mfma_f32_16x16x32_bf16(pah, vfh, oacc, 0, 0, 0);
      oacc = __builtin_amdgcn_mfma_f32_16x16x32_bf16(pah, vfl, oacc, 0, 0, 0);
      oacc = __builtin_amdgcn_mfma_f32_16x16x32_bf16(pal, vfh, oacc, 0, 0, 0);
    }
    __syncthreads();
  }

  // epilogue: oacc row q=quad*4+r, col d=wid*16+l15; write TILED attn:
  // p = b*T+t (row), kd = h*64+d (col)
  const int kd = h * DH_ + wid * 16 + l15;
  const int kpart = (kd >> 5) * 2 * 512 + ((kd >> 3) & 3) * 16 * 8 + (kd & 7);
#pragma unroll
  for (int r = 0; r < 4; r++) {
    const int q = quad * 4 + r;
    if (q < nqt) {
      const float inv = 0.5f / larr[q];
      const int t = ql[qlo + q];
      const int p = b * T_ + t;
      const long off = (long)(p >> 5) * 16384 + ((p >> 4) & 1) * 512
                       + (p & 15) * 8 + kpart;
      atomicAdd(attn + off, oacc[r] * inv);
    }
  }
}

// ---------------------------------------------------------------------------
extern "C" void kernel_launch(void* const* d_in, const int* in_sizes, int n_in,
                              void* d_out, int out_size, void* d_ws, size_t ws_size,
                              hipStream_t stream) {
  const float* query = (const float*)d_in[0];
  const float* key   = (const float*)d_in[1];
  const float* value = (const float*)d_in[2];
  const float* Wq = (const float*)d_in[3];
  const float* bq = (const float*)d_in[4];
  const float* Wk = (const float*)d_in[5];
  const float* bk = (const float*)d_in[6];
  const float* Wv = (const float*)d_in[7];
  const float* bv = (const float*)d_in[8];
  const float* Wo = (const float*)d_in[9];
  const float* bo = (const float*)d_in[10];
  const float* lshW = (const float*)d_in[11];
  const float* lshb = (const float*)d_in[12];

  const size_t MSZ = (size_t)M_ * E_;
  const size_t WSZ = (size_t)E_ * E_;
  float* Q    = (float*)d_ws;
  float* K    = Q + MSZ;
  float* V    = K + MSZ;
  float* attn = V + MSZ;
  int* qh     = (int*)(attn + MSZ);
  int* kh     = qh + NSEG * T_;
  int* klist  = kh + NSEG * T_;
  int* qlist  = klist + NSEG * T_;
  int* ntasks = qlist + NSEG * T_;
  int* koff   = ntasks + 1;
  int* qoff   = koff + NSEG * (NBUCKET + 1);
  int* tasks  = qoff + NSEG * (NBUCKET + 1);
  uint16_t* Woh = (uint16_t*)(((uintptr_t)(tasks + MAXTASK) + 15) & ~(uintptr_t)15);
  uint16_t* Wol = Woh + WSZ;
  uint16_t* Wqh = Wol + WSZ;
  uint16_t* Wql = Wqh + WSZ;
  uint16_t* Wkh = Wql + WSZ;
  uint16_t* Wkl = Wkh + WSZ;
  uint16_t* Wvh = Wkl + WSZ;
  uint16_t* Wvl = Wvh + WSZ;
  uint16_t* Xqh = Wvl + WSZ;
  uint16_t* Xql = Xqh + MSZ;
  uint16_t* Xkh = Xql + MSZ;
  uint16_t* Xkl = Xkh + MSZ;
  uint16_t* Xvh = Xkl + MSZ;
  uint16_t* Xvl = Xvh + MSZ;
  uint16_t* Lwh = Xvl + MSZ;
  uint16_t* Lwl = Lwh + (size_t)NROUND * DH_ * DH_;

  prep_kernel<<<dim3(1921), 256, 0, stream>>>(
      query, key, value, Wq, Wk, Wv, Wo, lshW,
      Xqh, Xql, Xkh, Xkl, Xvh, Xvl,
      Wqh, Wql, Wkh, Wkl, Wvh, Wvl, Woh, Wol,
      Lwh, Lwl, attn, ntasks);
  proj_mfma<<<dim3(M_ / 128, E_ / 64, 3), 256, 0, stream>>>(
      Xqh, Xql, Xkh, Xkl, Xvh, Xvl,
      Wqh, Wql, Wkh, Wkl, Wvh, Wvl,
      bq, bk, bv, Q, K, V);
  hash_mfma<<<dim3(M_ * H_ / 128, 4), 256, 0, stream>>>(
      Q, K, Lwh, Lwl, lshb, qh, kh);
  hist_scatter<<<dim3(NSEG, 2), 256, 0, stream>>>(
      kh, qh, koff, qoff, klist, qlist, ntasks, tasks);
  attn_task<<<dim3(MAXTASK), 256, 0, stream>>>(
      Q, K, V, qlist, qoff, klist, koff, tasks, ntasks, attn);
  mfma_gemm<<<dim3(M_ / 128, E_ / 64), 256, 0, stream>>>(
      attn, Woh, Wol, bo, (float*)d_out);
}